// Round 1
// 338.184 us; speedup vs baseline: 1.2585x; 1.2585x over previous
//
#include <hip/hip_runtime.h>
#include <hip/hip_bf16.h>
#include <math.h>

using bf16 = __hip_bfloat16;

#define L_SEQ   2048
#define DMODEL  256
#define DINNER  1024
#define DSTATE  128
#define NH      16
#define HD      64
#define CONVDIM 1280
#define DPROJ   2320
#define NCHK    8
#define CT      256
#define BATCH   2
#define M_TOT   (BATCH*L_SEQ)

#define ACS_N   (BATCH*NH*NCHK*CT)
#define ST_N    ((size_t)BATCH*NCHK*NH*HD*DSTATE)
#define CB_N    ((size_t)BATCH*NCHK*CT*CT)

typedef __bf16 bf16x8_t __attribute__((ext_vector_type(8)));
typedef float  f32x4_t  __attribute__((ext_vector_type(4)));

__device__ __forceinline__ float tof(bf16 v){ return __bfloat162float(v); }
__device__ __forceinline__ bf16  tob(float v){ return __float2bfloat16(v); }
__device__ __forceinline__ float expdec(float a){ return expf(fminf(a, 0.f)); }

// ---------------- fp32 -> bf16 cast (all weights, one launch) --------------------
struct CastJob  { const float* src; bf16* dst; int n; };
struct CastJobs { CastJob j[5]; };

__global__ __launch_bounds__(256) void k_cast5(CastJobs jobs){
  CastJob jb = jobs.j[blockIdx.y];
  int i = (blockIdx.x*256 + threadIdx.x)*4;
  if (i < jb.n){
    float4 v = *(const float4*)(jb.src + i);
    jb.dst[i]   = tob(v.x); jb.dst[i+1] = tob(v.y);
    jb.dst[i+2] = tob(v.z); jb.dst[i+3] = tob(v.w);
  }
}

// ---------------- batch stats ----------------------------------------------------
__global__ __launch_bounds__(256) void k_stats1(const float* __restrict__ x, float2* __restrict__ pbuf){
  int b = blockIdx.y, blk = blockIdx.x, t = threadIdx.x;
  const float4* p = (const float4*)(x + (size_t)b*(DMODEL*L_SEQ) + (size_t)blk*4096);
  float s = 0.f, ss = 0.f;
  #pragma unroll
  for (int k = 0; k < 4; ++k){
    float4 v = p[t + k*256];
    s  += v.x + v.y + v.z + v.w;
    ss += v.x*v.x + v.y*v.y + v.z*v.z + v.w*v.w;
  }
  for (int o = 32; o > 0; o >>= 1){ s += __shfl_down(s, o, 64); ss += __shfl_down(ss, o, 64); }
  __shared__ float sh[8];
  if ((t & 63) == 0){ sh[(t>>6)*2] = s; sh[(t>>6)*2+1] = ss; }
  __syncthreads();
  if (t == 0){
    s  = sh[0]+sh[2]+sh[4]+sh[6];
    ss = sh[1]+sh[3]+sh[5]+sh[7];
    pbuf[b*128 + blk] = make_float2(s, ss);
  }
}

__global__ __launch_bounds__(128) void k_stats2(const float2* __restrict__ pbuf, float* __restrict__ stats){
  int b = blockIdx.x, t = threadIdx.x;
  float2 v = pbuf[b*128 + t];
  float s = v.x, ss = v.y;
  for (int o = 32; o > 0; o >>= 1){ s += __shfl_down(s, o, 64); ss += __shfl_down(ss, o, 64); }
  __shared__ float sh[4];
  if ((t & 63) == 0){ sh[(t>>6)*2] = s; sh[(t>>6)*2+1] = ss; }
  __syncthreads();
  if (t == 0){
    s  = sh[0]+sh[2];
    ss = sh[1]+sh[3];
    float inv = 1.f/(float)(DMODEL*L_SEQ);
    float mu = s*inv, var = ss*inv - mu*mu;
    stats[0 + b*2] = mu; stats[1 + b*2] = rsqrtf(fmaxf(var, 0.f) + 1.1920929e-07f);
  }
}

// ---------------- GroupNorm + transpose ------------------------------------------
__global__ __launch_bounds__(256) void k_t(const float* __restrict__ x, const float* __restrict__ gw,
                                           const float* __restrict__ gb, const float* __restrict__ stats,
                                           bf16* __restrict__ t_out){
  __shared__ float tile[64][65];
  int l0 = blockIdx.x*64, c0 = blockIdx.y*64, b = blockIdx.z;
  float mu = stats[b*2], istd = stats[b*2+1];
  int tid = threadIdx.x;
  int lx = tid & 63, cy = tid >> 6;
  for (int cc = cy; cc < 64; cc += 4){
    float v = x[(size_t)b*DMODEL*L_SEQ + (size_t)(c0+cc)*L_SEQ + l0+lx];
    tile[cc][lx] = (v - mu)*istd;
  }
  __syncthreads();
  int cx = tid & 63, ly = tid >> 6;
  float w = gw[c0+cx], bb = gb[c0+cx];
  for (int ll = ly; ll < 64; ll += 4)
    t_out[((size_t)(b*L_SEQ) + l0+ll)*DMODEL + c0+cx] = tob(tile[cx][ll]*w + bb);
}

// ---------------- MFMA GEMM 128x64, dir-batched (z), direct epilogue -------------
template<class Epi>
__global__ __launch_bounds__(256) void gemm_epi(const bf16* __restrict__ A, int lda,
                                                const bf16* __restrict__ B, int ldb,
                                                int M, int N, int K, Epi epi){
  __shared__ __align__(16) bf16 lds[2][(128+64)*40];
  int dir = blockIdx.z;
  const bf16* Bd = B + (size_t)dir*(size_t)N*ldb;
  int m0 = blockIdx.x*128, n0 = blockIdx.y*64;
  int t = threadIdx.x;
  int wave = t >> 6, lane = t & 63;
  int wm = (wave & 1)*64, wn = (wave >> 1)*32;
  int lrow = lane & 15, quad = lane >> 4, lk8 = quad*8;

  int r0 = t >> 2, o0 = (t & 3)*8;
  int r1 = r0 + 64;
  int am0 = m0 + r0, am1 = m0 + r1;
  if (dir){
    am0 = (am0 & ~(L_SEQ-1)) | ((L_SEQ-1) - (am0 & (L_SEQ-1)));
    am1 = (am1 & ~(L_SEQ-1)) | ((L_SEQ-1) - (am1 & (L_SEQ-1)));
  }
  int bn = n0 + r0; if (bn > N-1) bn = N-1;
  const bf16* Ap0 = A + (size_t)am0*lda + o0;
  const bf16* Ap1 = A + (size_t)am1*lda + o0;
  const bf16* Bp  = Bd + (size_t)bn*ldb + o0;

  f32x4_t acc[4][2];
  #pragma unroll
  for (int i = 0; i < 4; ++i){ acc[i][0] = (f32x4_t){0,0,0,0}; acc[i][1] = (f32x4_t){0,0,0,0}; }

  int nit = K >> 5;
  uint4 a0 = *(const uint4*)Ap0;
  uint4 a1 = *(const uint4*)Ap1;
  uint4 b0 = *(const uint4*)Bp;
  int st = 0;
  *(uint4*)&lds[0][r0*40 + o0] = a0;
  *(uint4*)&lds[0][r1*40 + o0] = a1;
  *(uint4*)&lds[0][(128 + r0)*40 + o0] = b0;
  __syncthreads();
  for (int it = 0; it < nit; ++it){
    bool more = (it+1 < nit);
    if (more){
      int kk = (it+1) << 5;
      a0 = *(const uint4*)(Ap0 + kk);
      a1 = *(const uint4*)(Ap1 + kk);
      b0 = *(const uint4*)(Bp + kk);
    }
    const bf16* cs = lds[st];
    bf16x8_t af[4], bfr[2];
    #pragma unroll
    for (int mi = 0; mi < 4; ++mi) af[mi] = *(const bf16x8_t*)&cs[(wm + mi*16 + lrow)*40 + lk8];
    #pragma unroll
    for (int ni = 0; ni < 2; ++ni) bfr[ni] = *(const bf16x8_t*)&cs[(128 + wn + ni*16 + lrow)*40 + lk8];
    #pragma unroll
    for (int mi = 0; mi < 4; ++mi)
      #pragma unroll
      for (int ni = 0; ni < 2; ++ni)
        acc[mi][ni] = __builtin_amdgcn_mfma_f32_16x16x32_bf16(af[mi], bfr[ni], acc[mi][ni], 0, 0, 0);
    if (more){
      st ^= 1;
      *(uint4*)&lds[st][r0*40 + o0] = a0;
      *(uint4*)&lds[st][r1*40 + o0] = a1;
      *(uint4*)&lds[st][(128 + r0)*40 + o0] = b0;
      __syncthreads();
    }
  }
  #pragma unroll
  for (int mi = 0; mi < 4; ++mi)
    #pragma unroll
    for (int ni = 0; ni < 2; ++ni)
      #pragma unroll
      for (int r = 0; r < 4; ++r){
        int m = m0 + wm + mi*16 + quad*4 + r;
        int n = n0 + wn + ni*16 + lrow;
        if (m < M && n < N) epi(dir, m, n, acc[mi][ni][r]);
      }
}

// ---------------- MFMA GEMM 128x64, split-K + dir (grid.z), fp32 atomic ---------
__global__ __launch_bounds__(256) void gemm_atomic2(const bf16* __restrict__ A, int lda,
                                                    const bf16* __restrict__ B, int ldb,
                                                    int M, int N, int K, float* __restrict__ scr){
  __shared__ __align__(16) bf16 lds[2][(128+64)*40];
  int zz = blockIdx.z; int dir = zz & 1; int kz = zz >> 1;
  const bf16* Ad = A + (size_t)dir*(size_t)M_TOT*DINNER;
  const bf16* Bd = B + (size_t)dir*(size_t)DMODEL*DINNER;
  float* sd = scr + (size_t)dir*(size_t)M_TOT*DMODEL;
  int m0 = blockIdx.x*128, n0 = blockIdx.y*64;
  int kc = K >> 2;
  int ks = kz * kc;
  int t = threadIdx.x;
  int wave = t >> 6, lane = t & 63;
  int wm = (wave & 1)*64, wn = (wave >> 1)*32;
  int lrow = lane & 15, quad = lane >> 4, lk8 = quad*8;

  int r0 = t >> 2, o0 = (t & 3)*8;
  int r1 = r0 + 64;
  const bf16* Ap0 = Ad + (size_t)(m0 + r0)*lda + ks + o0;
  const bf16* Ap1 = Ad + (size_t)(m0 + r1)*lda + ks + o0;
  const bf16* Bp  = Bd + (size_t)(n0 + r0)*ldb + ks + o0;

  f32x4_t acc[4][2];
  #pragma unroll
  for (int i = 0; i < 4; ++i){ acc[i][0] = (f32x4_t){0,0,0,0}; acc[i][1] = (f32x4_t){0,0,0,0}; }

  int nit = kc >> 5;
  uint4 a0 = *(const uint4*)Ap0;
  uint4 a1 = *(const uint4*)Ap1;
  uint4 b0 = *(const uint4*)Bp;
  int st = 0;
  *(uint4*)&lds[0][r0*40 + o0] = a0;
  *(uint4*)&lds[0][r1*40 + o0] = a1;
  *(uint4*)&lds[0][(128 + r0)*40 + o0] = b0;
  __syncthreads();
  for (int it = 0; it < nit; ++it){
    bool more = (it+1 < nit);
    if (more){
      int kk = (it+1) << 5;
      a0 = *(const uint4*)(Ap0 + kk);
      a1 = *(const uint4*)(Ap1 + kk);
      b0 = *(const uint4*)(Bp + kk);
    }
    const bf16* cs = lds[st];
    bf16x8_t af[4], bfr[2];
    #pragma unroll
    for (int mi = 0; mi < 4; ++mi) af[mi] = *(const bf16x8_t*)&cs[(wm + mi*16 + lrow)*40 + lk8];
    #pragma unroll
    for (int ni = 0; ni < 2; ++ni) bfr[ni] = *(const bf16x8_t*)&cs[(128 + wn + ni*16 + lrow)*40 + lk8];
    #pragma unroll
    for (int mi = 0; mi < 4; ++mi)
      #pragma unroll
      for (int ni = 0; ni < 2; ++ni)
        acc[mi][ni] = __builtin_amdgcn_mfma_f32_16x16x32_bf16(af[mi], bfr[ni], acc[mi][ni], 0, 0, 0);
    if (more){
      st ^= 1;
      *(uint4*)&lds[st][r0*40 + o0] = a0;
      *(uint4*)&lds[st][r1*40 + o0] = a1;
      *(uint4*)&lds[st][(128 + r0)*40 + o0] = b0;
      __syncthreads();
    }
  }
  #pragma unroll
  for (int mi = 0; mi < 4; ++mi)
    #pragma unroll
    for (int ni = 0; ni < 2; ++ni)
      #pragma unroll
      for (int r = 0; r < 4; ++r){
        int m = m0 + wm + mi*16 + quad*4 + r;
        int n = n0 + wn + ni*16 + lrow;
        atomicAdd(&sd[(size_t)m*N + n], acc[mi][ni][r]);
      }
}

// ---------------- plain split-K atomic GEMM (final projection) -------------------
__global__ __launch_bounds__(256) void gemm_atomic(const bf16* __restrict__ A, int lda,
                                                   const bf16* __restrict__ B, int ldb,
                                                   int M, int N, int K, float* __restrict__ scr){
  __shared__ __align__(16) bf16 lds[2][(128+64)*40];
  int m0 = blockIdx.x*128, n0 = blockIdx.y*64;
  int kc = K / gridDim.z;
  int ks = blockIdx.z * kc;
  int t = threadIdx.x;
  int wave = t >> 6, lane = t & 63;
  int wm = (wave & 1)*64, wn = (wave >> 1)*32;
  int lrow = lane & 15, quad = lane >> 4, lk8 = quad*8;

  int r0 = t >> 2, o0 = (t & 3)*8;
  int r1 = r0 + 64;
  const bf16* Ap0 = A + (size_t)(m0 + r0)*lda + ks + o0;
  const bf16* Ap1 = A + (size_t)(m0 + r1)*lda + ks + o0;
  const bf16* Bp  = B + (size_t)(n0 + r0)*ldb + ks + o0;

  f32x4_t acc[4][2];
  #pragma unroll
  for (int i = 0; i < 4; ++i){ acc[i][0] = (f32x4_t){0,0,0,0}; acc[i][1] = (f32x4_t){0,0,0,0}; }

  int nit = kc >> 5;
  uint4 a0 = *(const uint4*)Ap0;
  uint4 a1 = *(const uint4*)Ap1;
  uint4 b0 = *(const uint4*)Bp;
  int st = 0;
  *(uint4*)&lds[0][r0*40 + o0] = a0;
  *(uint4*)&lds[0][r1*40 + o0] = a1;
  *(uint4*)&lds[0][(128 + r0)*40 + o0] = b0;
  __syncthreads();
  for (int it = 0; it < nit; ++it){
    bool more = (it+1 < nit);
    if (more){
      int kk = (it+1) << 5;
      a0 = *(const uint4*)(Ap0 + kk);
      a1 = *(const uint4*)(Ap1 + kk);
      b0 = *(const uint4*)(Bp + kk);
    }
    const bf16* cs = lds[st];
    bf16x8_t af[4], bfr[2];
    #pragma unroll
    for (int mi = 0; mi < 4; ++mi) af[mi] = *(const bf16x8_t*)&cs[(wm + mi*16 + lrow)*40 + lk8];
    #pragma unroll
    for (int ni = 0; ni < 2; ++ni) bfr[ni] = *(const bf16x8_t*)&cs[(128 + wn + ni*16 + lrow)*40 + lk8];
    #pragma unroll
    for (int mi = 0; mi < 4; ++mi)
      #pragma unroll
      for (int ni = 0; ni < 2; ++ni)
        acc[mi][ni] = __builtin_amdgcn_mfma_f32_16x16x32_bf16(af[mi], bfr[ni], acc[mi][ni], 0, 0, 0);
    if (more){
      st ^= 1;
      *(uint4*)&lds[st][r0*40 + o0] = a0;
      *(uint4*)&lds[st][r1*40 + o0] = a1;
      *(uint4*)&lds[st][(128 + r0)*40 + o0] = b0;
      __syncthreads();
    }
  }
  #pragma unroll
  for (int mi = 0; mi < 4; ++mi)
    #pragma unroll
    for (int ni = 0; ni < 2; ++ni)
      #pragma unroll
      for (int r = 0; r < 4; ++r){
        int m = m0 + wm + mi*16 + quad*4 + r;
        int n = n0 + wn + ni*16 + lrow;
        atomicAdd(&scr[(size_t)m*N + n], acc[mi][ni][r]);
      }
}

struct EpiInProj {
  bf16* z; bf16* xbc; float* dt; const float* db0; const float* db1;
  __device__ void operator()(int dir, int m, int n, float v) const {
    size_t mm = (size_t)dir*M_TOT + m;
    if (n < DINNER) z[mm*DINNER + n] = tob(v);
    else if (n < DINNER+CONVDIM) xbc[mm*CONVDIM + (n-DINNER)] = tob(v);
    else {
      int h = n - (DINNER+CONVDIM);
      float xx = v + (dir ? db1 : db0)[h];
      dt[mm*NH + h] = (xx > 20.f) ? xx : log1pf(expf(xx));
    }
  }
};

// ---------------- post: out-proj epilogue (scr + t -> r, dir-batched) ------------
__global__ __launch_bounds__(256) void post_outproj(const float* __restrict__ scr, const bf16* __restrict__ tb,
                                                    bf16* __restrict__ r){
  int n = threadIdx.x;
  int zb = blockIdx.x;
  int dir = zb >> 9; int mb = (zb & 511)*8;
  const float* sd = scr + (size_t)dir*(size_t)M_TOT*DMODEL;
  for (int i = 0; i < 8; ++i){
    int mm = mb + i;
    int pm = dir ? ((mm & ~(L_SEQ-1)) | ((L_SEQ-1) - (mm & (L_SEQ-1)))) : mm;
    r[(size_t)pm*(2*DMODEL) + dir*DMODEL + n] = tob(sd[(size_t)mm*DMODEL + n] + tof(tb[(size_t)pm*DMODEL + n]));
  }
}

// ---------------- post: final epilogue (scr + pb + x -> out, transposed) ---------
__global__ __launch_bounds__(256) void post_final(const float* __restrict__ scr, const float* __restrict__ x,
                                                  const float* __restrict__ pb, float* __restrict__ out){
  __shared__ float tile[64][65];
  int l0 = blockIdx.x*64, n0 = blockIdx.y*64, b = blockIdx.z;
  int tid = threadIdx.x;
  int nx = tid & 63, ly = tid >> 6;
  for (int ll = ly; ll < 64; ll += 4)
    tile[ll][nx] = scr[((size_t)(b*L_SEQ) + l0+ll)*DMODEL + n0+nx];
  __syncthreads();
  int lx = tid & 63, ny = tid >> 6;
  for (int nn = ny; nn < 64; nn += 4){
    int n = n0 + nn;
    size_t xi = (size_t)b*DMODEL*L_SEQ + (size_t)n*L_SEQ + l0+lx;
    out[xi] = tile[lx][nn] + pb[n] + x[xi];
  }
}

// ---------------- depthwise causal conv + SiLU, dir-batched ----------------------
__global__ __launch_bounds__(256) void k_conv(const bf16* __restrict__ xraw, const float* __restrict__ cw0,
                                              const float* __restrict__ cb0, const float* __restrict__ cw1,
                                              const float* __restrict__ cb1, bf16* __restrict__ xconv){
  int ch = blockIdx.x*256 + threadIdx.x;
  int l = blockIdx.y, z = blockIdx.z;
  int b = z & 1, dir = z >> 1;
  const float* cw = dir ? cw1 : cw0;
  const float* cb = dir ? cb1 : cb0;
  const bf16* xr = xraw  + (size_t)dir*((size_t)M_TOT*CONVDIM);
  bf16* xcv      = xconv + (size_t)dir*((size_t)M_TOT*CONVDIM);
  float acc = cb[ch];
  #pragma unroll
  for (int k = 0; k < 4; ++k){
    int ls = l - 3 + k;
    if (ls >= 0)
      acc += tof(xr[((size_t)(b*L_SEQ) + ls)*CONVDIM + ch]) * cw[ch*4 + k];
  }
  xcv[((size_t)(b*L_SEQ) + l)*CONVDIM + ch] = tob(acc / (1.f + expf(-acc)));
}

// ---------------- per-(dir,b,h,chunk) inclusive cumsum of A ----------------------
__global__ __launch_bounds__(256) void k_scan(const float* __restrict__ dt, const float* __restrict__ Al0,
                                              const float* __restrict__ Al1, float* __restrict__ A_cs){
  int id0 = blockIdx.x;
  int dir = id0 >> 8; int id = id0 & 255;
  int ch = id & 7; int bh = id >> 3; int h = bh & 15; int b = bh >> 4;
  const float* Alog = dir ? Al1 : Al0;
  const float* dtp = dt + (size_t)dir*((size_t)M_TOT*NH);
  float* acsd = A_cs + (size_t)dir*ACS_N;
  int l = threadIdx.x;
  int gl = ch*CT + l;
  float a = -expf(Alog[h]) * dtp[((size_t)(b*L_SEQ)+gl)*NH + h];
  __shared__ float s[256];
  s[l] = a; __syncthreads();
  for (int off = 1; off < 256; off <<= 1){
    float v = (l >= off) ? s[l-off] : 0.f;
    __syncthreads();
    s[l] += v;
    __syncthreads();
  }
  acsd[(size_t)id*CT + l] = s[l];
}

// ---------------- per-chunk states (vectorized staging, dir-batched) -------------
__global__ __launch_bounds__(256) void k_states(const bf16* __restrict__ xconv, const float* __restrict__ dt,
                                                const float* __restrict__ A_cs, float* __restrict__ states){
  int id0 = blockIdx.x;
  int dir = id0 >> 8; int id = id0 & 255;
  int h = id & 15; int bc = id >> 4; int ch = bc & 7; int b = bc >> 3;
  int t = threadIdx.x;
  __shared__ float w_s[64];
  __shared__ __align__(16) float Xs[64*64];
  __shared__ __align__(16) float Bs[64*128];
  const bf16* xc = xconv + (size_t)dir*((size_t)M_TOT*CONVDIM);
  const float* dtp = dt + (size_t)dir*((size_t)M_TOT*NH);
  const float* acs = A_cs + (size_t)dir*ACS_N + (size_t)((b*NH+h)*NCHK + ch)*CT;
  float alast = acs[CT-1];
  float acc[4][8] = {};
  int tx = t & 15, ty = t >> 4;
  size_t rowbase = (size_t)(b*L_SEQ) + ch*CT;
  for (int lt = 0; lt < 4; ++lt){
    int lbase = lt*64;
    if (t < 64)
      w_s[t] = dtp[(rowbase + lbase + t)*NH + h] * expdec(alast - acs[lbase + t]);
    __syncthreads();
    #pragma unroll
    for (int it = 0; it < 2; ++it){
      int idx = t + it*256; int l = idx >> 3; int p0 = (idx & 7)*8;
      bf16x8_t v = *(const bf16x8_t*)&xc[(rowbase + lbase + l)*CONVDIM + h*HD + p0];
      float w = w_s[l];
      float4 f0 = { (float)v[0]*w, (float)v[1]*w, (float)v[2]*w, (float)v[3]*w };
      float4 f1 = { (float)v[4]*w, (float)v[5]*w, (float)v[6]*w, (float)v[7]*w };
      *(float4*)&Xs[l*64 + p0]     = f0;
      *(float4*)&Xs[l*64 + p0 + 4] = f1;
    }
    #pragma unroll
    for (int it = 0; it < 4; ++it){
      int idx = t + it*256; int l = idx >> 4; int n0 = (idx & 15)*8;
      bf16x8_t v = *(const bf16x8_t*)&xc[(rowbase + lbase + l)*CONVDIM + DINNER + n0];
      float4 f0 = { (float)v[0], (float)v[1], (float)v[2], (float)v[3] };
      float4 f1 = { (float)v[4], (float)v[5], (float)v[6], (float)v[7] };
      *(float4*)&Bs[l*128 + n0]     = f0;
      *(float4*)&Bs[l*128 + n0 + 4] = f1;
    }
    __syncthreads();
    for (int l = 0; l < 64; ++l){
      float4 pv = *(const float4*)&Xs[l*64 + ty*4];
      float4 na = *(const float4*)&Bs[l*128 + tx*8];
      float4 nb = *(const float4*)&Bs[l*128 + tx*8 + 4];
      float pr[4] = {pv.x, pv.y, pv.z, pv.w};
      float nr[8] = {na.x, na.y, na.z, na.w, nb.x, nb.y, nb.z, nb.w};
      #pragma unroll
      for (int i = 0; i < 4; ++i)
        #pragma unroll
        for (int j = 0; j < 8; ++j) acc[i][j] += pr[i]*nr[j];
    }
    __syncthreads();
  }
  float* so = states + (size_t)dir*ST_N + (size_t)id*HD*DSTATE;
  #pragma unroll
  for (int i = 0; i < 4; ++i)
    #pragma unroll
    for (int j = 0; j < 8; ++j)
      so[(ty*4+i)*DSTATE + tx*8+j] = acc[i][j];
}

// ---------------- inter-chunk recurrence (one element per thread) ----------------
__global__ __launch_bounds__(256) void k_recur(float* __restrict__ states, const float* __restrict__ A_cs){
  int blk = blockIdx.x;                 // [0, 2048): (dir,b,h) x 32 blocks
  int bh2 = blk >> 5;
  int e = (blk & 31)*256 + threadIdx.x; // [0, HD*DSTATE)
  int dir = bh2 >> 5; int bh = bh2 & 31;
  int h = bh & 15, b = bh >> 4;
  const float* ac = A_cs + (size_t)dir*ACS_N;
  float* st = states + (size_t)dir*ST_N;
  float s = 0.f;
  #pragma unroll
  for (int ch = 0; ch < NCHK; ++ch){
    float dec = expdec(ac[((size_t)(bh*NCHK+ch))*CT + CT-1]);
    size_t off = (size_t)(((b*NCHK+ch)*NH)+h)*HD*DSTATE + e;
    float cur = st[off];
    st[off] = s;
    s = s*dec + cur;
  }
}

// ---------------- CB = C · B^T per (dir,b,chunk) ---------------------------------
__global__ __launch_bounds__(256) void k_cb(const bf16* __restrict__ xconv, float* __restrict__ CB){
  int zz = blockIdx.z;
  int dir = zz >> 4; int b = (zz >> 3) & 1; int ch = zz & 7;
  int m0 = blockIdx.x*64, n0 = blockIdx.y*64;
  if (n0 > m0 + 63) return;
  const bf16* base = xconv + (size_t)dir*((size_t)M_TOT*CONVDIM) + (size_t)(b*L_SEQ + ch*CT)*CONVDIM;
  const bf16* Crow = base + DINNER + DSTATE;
  const bf16* Brow = base + DINNER;
  __shared__ __align__(16) float As[16][68];
  __shared__ __align__(16) float Bs[16][68];
  int t = threadIdx.x, tx = t & 15, ty = t >> 4;
  float acc[4][4] = {};
  int lr = t >> 2, lk = (t & 3)*4;
  for (int k0 = 0; k0 < DSTATE; k0 += 16){
    #pragma unroll
    for (int j = 0; j < 4; ++j) As[lk+j][lr] = tof(Crow[(size_t)(m0+lr)*CONVDIM + k0+lk+j]);
    #pragma unroll
    for (int j = 0; j < 4; ++j) Bs[lk+j][lr] = tof(Brow[(size_t)(n0+lr)*CONVDIM + k0+lk+j]);
    __syncthreads();
    #pragma unroll
    for (int kk = 0; kk < 16; ++kk){
      float4 av = *(const float4*)&As[kk][ty*4];
      float4 bv = *(const float4*)&Bs[kk][tx*4];
      acc[0][0] += av.x*bv.x; acc[0][1] += av.x*bv.y; acc[0][2] += av.x*bv.z; acc[0][3] += av.x*bv.w;
      acc[1][0] += av.y*bv.x; acc[1][1] += av.y*bv.y; acc[1][2] += av.y*bv.z; acc[1][3] += av.y*bv.w;
      acc[2][0] += av.z*bv.x; acc[2][1] += av.z*bv.y; acc[2][2] += av.z*bv.z; acc[2][3] += av.z*bv.w;
      acc[3][0] += av.w*bv.x; acc[3][1] += av.w*bv.y; acc[3][2] += av.w*bv.z; acc[3][3] += av.w*bv.w;
    }
    __syncthreads();
  }
  float* outp = CB + (size_t)dir*CB_N + (size_t)(b*NCHK+ch)*CT*CT;
  #pragma unroll
  for (int i = 0; i < 4; ++i)
    #pragma unroll
    for (int j = 0; j < 4; ++j)
      outp[(m0+ty*4+i)*CT + n0+tx*4+j] = acc[i][j];
}

// ---------------- Y = (L*CB)@X + exp(Acs)*(C@NS)  (MFMA, dir-batched) ------------
__global__ __launch_bounds__(256) void k_y_mfma(const bf16* __restrict__ xconv, const float* __restrict__ dt,
                                                const float* __restrict__ A_cs, const float* __restrict__ CB,
                                                const float* __restrict__ ns, bf16* __restrict__ y){
  int id0 = blockIdx.x;
  int dir = id0 >> 9; int id = id0 & 511;
  int hh = id & 1; int r = id >> 1; int h = r & 15; int bc = r >> 4; int ch = bc & 7; int b = bc >> 3;
  int t = threadIdx.x;
  int lane = t & 63;
  int lrow = lane & 15, quad = lane >> 4;

  __shared__ __align__(16) bf16 Xs[64*264];
  __shared__ __align__(16) bf16 NSs[64*136];
  __shared__ float acs_s[CT];

  const bf16* xc = xconv + (size_t)dir*((size_t)M_TOT*CONVDIM);
  const float* dtp = dt + (size_t)dir*((size_t)M_TOT*NH);
  const float* acs = A_cs + (size_t)dir*ACS_N + (size_t)((b*NH+h)*NCHK + ch)*CT;
  const float* cbz = CB + (size_t)dir*CB_N + (size_t)(b*NCHK+ch)*CT*CT;
  const float* nsp = ns + (size_t)dir*ST_N + (size_t)(((b*NCHK+ch)*NH)+h)*HD*DSTATE;
  bf16* yp = y + (size_t)dir*((size_t)M_TOT*DINNER);
  size_t rowbase = (size_t)(b*L_SEQ + ch*CT);
  acs_s[t] = acs[t];

  // X staging: vectorized bf16x8 loads, scatter into [p][s] layout
  #pragma unroll
  for (int it = 0; it < 8; ++it){
    int idx = t + it*256;
    int s = idx >> 3, p0 = (idx & 7)*8;
    float dtv = dtp[(rowbase + s)*NH + h];
    bf16x8_t v = *(const bf16x8_t*)&xc[(rowbase + s)*CONVDIM + h*HD + p0];
    #pragma unroll
    for (int j = 0; j < 8; ++j)
      Xs[(p0+j)*264 + s] = tob((float)v[j] * dtv);
  }
  for (int it = 0; it < 8; ++it){
    int idx = t + it*256;
    int n4 = (idx & 31)*4, p = idx >> 5;
    float4 v = *(const float4*)(nsp + p*DSTATE + n4);
    bf16* w = &NSs[p*136 + n4];
    w[0] = tob(v.x); w[1] = tob(v.y); w[2] = tob(v.z); w[3] = tob(v.w);
  }
  __syncthreads();

  int wave = t >> 6;
  int row0 = hh*128 + wave*32;
  float al0 = acs_s[row0 + lrow];
  float al1 = acs_s[row0 + 16 + lrow];
  float acs_r0 = acs_s[row0];

  f32x4_t acc[2][4];
  #pragma unroll
  for (int i = 0; i < 2; ++i)
    #pragma unroll
    for (int j = 0; j < 4; ++j) acc[i][j] = (f32x4_t){0.f,0.f,0.f,0.f};

  int nst = (row0 + 32) >> 5;
  for (int st = 0; st < nst; ++st){
    int s0 = st*32;
    if (s0 + 31 < row0 && (acs_r0 - acs_s[s0+31]) < -30.f) continue;
    bf16x8_t bq[4];
    #pragma unroll
    for (int nt = 0; nt < 4; ++nt)
      bq[nt] = *(const bf16x8_t*)&Xs[(nt*16+lrow)*264 + s0 + quad*8];
    bf16x8_t af[2];
    #pragma unroll
    for (int mt = 0; mt < 2; ++mt){
      int l = row0 + mt*16 + lrow;
      float al = mt ? al1 : al0;
      const float* cbrow = cbz + (size_t)l*CT + s0 + quad*8;
      float4 c0 = *(const float4*)cbrow;
      float4 c1 = *(const float4*)(cbrow + 4);
      float cv[8] = {c0.x,c0.y,c0.z,c0.w,c1.x,c1.y,c1.z,c1.w};
      union { bf16x8_t v; __bf16 e[8]; } wa;
      #pragma unroll
      for (int j = 0; j < 8; ++j){
        int s = s0 + quad*8 + j;
        float w = (s <= l) ? expf(fminf(al - acs_s[s], 0.f)) * cv[j] : 0.f;
        wa.e[j] = (__bf16)w;
      }
      af[mt] = wa.v;
    }
    #pragma unroll
    for (int mt = 0; mt < 2; ++mt)
      #pragma unroll
      for (int nt = 0; nt < 4; ++nt)
        acc[mt][nt] = __builtin_amdgcn_mfma_f32_16x16x32_bf16(af[mt], bq[nt], acc[mt][nt], 0, 0, 0);
  }

  float el0 = expf(fminf(al0, 0.f));
  float el1 = expf(fminf(al1, 0.f));
  #pragma unroll
  for (int kt = 0; kt < 4; ++kt){
    int n0 = kt*32;
    bf16x8_t bq[4];
    #pragma unroll
    for (int nt = 0; nt < 4; ++nt)
      bq[nt] = *(const bf16x8_t*)&NSs[(nt*16+lrow)*136 + n0 + quad*8];
    bf16x8_t af[2];
    #pragma unroll
    for (int mt = 0; mt < 2; ++mt){
      int l = row0 + mt*16 + lrow;
      float el = mt ? el1 : el0;
      union { bf16x8_t v; __bf16 e[8]; } cu;
      cu.v = *(const bf16x8_t*)&xc[(rowbase + l)*CONVDIM + DINNER + DSTATE + n0 + quad*8];
      union { bf16x8_t v; __bf16 e[8]; } wa;
      #pragma unroll
      for (int j = 0; j < 8; ++j) wa.e[j] = (__bf16)((float)cu.e[j] * el);
      af[mt] = wa.v;
    }
    #pragma unroll
    for (int mt = 0; mt < 2; ++mt)
      #pragma unroll
      for (int nt = 0; nt < 4; ++nt)
        acc[mt][nt] = __builtin_amdgcn_mfma_f32_16x16x32_bf16(af[mt], bq[nt], acc[mt][nt], 0, 0, 0);
  }

  #pragma unroll
  for (int mt = 0; mt < 2; ++mt)
    #pragma unroll
    for (int nt = 0; nt < 4; ++nt)
      #pragma unroll
      for (int rr = 0; rr < 4; ++rr){
        int l = row0 + mt*16 + quad*4 + rr;
        int p = nt*16 + lrow;
        yp[(rowbase + l)*DINNER + h*HD + p] = tob(acc[mt][nt][rr]);
      }
}

// ---------------- gate ((y + D*x) * silu(z)) + RMSNorm, dir-batched --------------
__global__ __launch_bounds__(256) void k_gaterms(const bf16* __restrict__ z, const float* __restrict__ nw0,
                                                 const float* __restrict__ nw1, const bf16* __restrict__ xconv,
                                                 const float* __restrict__ Dh0, const float* __restrict__ Dh1,
                                                 bf16* __restrict__ y){
  int m0 = blockIdx.x;
  int dir = m0 >> 12; int m = m0 & (M_TOT-1);
  int t = threadIdx.x;
  const float* nw = dir ? nw1 : nw0;
  const float* Dh = dir ? Dh1 : Dh0;
  float v[4]; float ss = 0.f;
  const bf16* zp = z + (size_t)dir*((size_t)M_TOT*DINNER) + (size_t)m*DINNER;
  const bf16* xc = xconv + (size_t)dir*((size_t)M_TOT*CONVDIM) + (size_t)m*CONVDIM;
  bf16* yp = y + (size_t)dir*((size_t)M_TOT*DINNER) + (size_t)m*DINNER;
  #pragma unroll
  for (int k = 0; k < 4; ++k){
    int j = t + k*256;
    float zv = tof(zp[j]);
    float raw = tof(yp[j]) + Dh[j>>6]*tof(xc[j]);
    float g = raw * (zv / (1.f + expf(-zv)));
    v[k] = g; ss += g*g;
  }
  for (int o = 32; o > 0; o >>= 1) ss += __shfl_down(ss, o, 64);
  __shared__ float sh[4];
  if ((t & 63) == 0) sh[t>>6] = ss;
  __syncthreads();
  ss = sh[0]+sh[1]+sh[2]+sh[3];
  float scale = rsqrtf(ss*(1.f/DINNER) + 1e-5f);
  #pragma unroll
  for (int k = 0; k < 4; ++k){
    int j = t + k*256;
    yp[j] = tob(v[k]*scale*nw[j]);
  }
}

extern "C" void kernel_launch(void* const* d_in, const int* in_sizes, int n_in,
                              void* d_out, int out_size, void* d_ws, size_t ws_size,
                              hipStream_t stream){
  (void)in_sizes; (void)n_in; (void)out_size; (void)ws_size;
  const float* x      = (const float*)d_in[0];
  const float* gn_w   = (const float*)d_in[1];
  const float* gn_b   = (const float*)d_in[2];
  const float* proj_w = (const float*)d_in[3];
  const float* proj_b = (const float*)d_in[4];
  float* out = (float*)d_out;

  char* wp = (char*)d_ws;
  auto alloc = [&](size_t bytes){ void* r = (void*)wp; wp += (bytes + 255) & ~(size_t)255; return r; };
  bf16*  t_buf  = (bf16*) alloc((size_t)M_TOT*DMODEL*2);
  bf16*  z_buf  = (bf16*) alloc((size_t)2*M_TOT*DINNER*2);
  bf16*  xraw   = (bf16*) alloc((size_t)2*M_TOT*CONVDIM*2);   // also reused as y (both dirs)
  bf16*  xconv  = (bf16*) alloc((size_t)2*M_TOT*CONVDIM*2);
  float* dt_buf = (float*)alloc((size_t)2*M_TOT*NH*4);
  float* acs    = (float*)alloc((size_t)2*ACS_N*4);
  float* states = (float*)alloc((size_t)2*ST_N*4);
  float* cb     = (float*)alloc((size_t)2*CB_N*4);
  bf16*  r_buf  = (bf16*) alloc((size_t)M_TOT*2*DMODEL*2);
  float* stats  = (float*)alloc(16);
  float2* pbuf  = (float2*)alloc(BATCH*128*sizeof(float2));
  bf16*  inw_bf   = (bf16*)alloc((size_t)2*DPROJ*DMODEL*2);
  bf16*  outw_bf  = (bf16*)alloc((size_t)2*DMODEL*DINNER*2);
  bf16*  projw_bf = (bf16*)alloc((size_t)DMODEL*2*DMODEL*2);
  float* scr      = (float*)alloc((size_t)3*M_TOT*DMODEL*4);   // [dir0][dir1][final]
  float* scr_fin  = scr + (size_t)2*M_TOT*DMODEL;
  bf16*  y_buf    = xraw;   // xraw dead after conv; y indexed (dir*M_TOT+m)*DINNER fits inside

  hipMemsetAsync(scr, 0, (size_t)3*M_TOT*DMODEL*4, stream);

  CastJobs jobs;
  jobs.j[0] = { (const float*)d_in[5],  inw_bf,                              DPROJ*DMODEL };
  jobs.j[1] = { (const float*)d_in[13], inw_bf + (size_t)DPROJ*DMODEL,       DPROJ*DMODEL };
  jobs.j[2] = { (const float*)d_in[12], outw_bf,                             DMODEL*DINNER };
  jobs.j[3] = { (const float*)d_in[20], outw_bf + (size_t)DMODEL*DINNER,     DMODEL*DINNER };
  jobs.j[4] = { proj_w,                 projw_bf,                            DMODEL*2*DMODEL };
  k_cast5<<<dim3(DPROJ*DMODEL/4/256, 5), 256, 0, stream>>>(jobs);

  k_stats1<<<dim3(128, BATCH), 256, 0, stream>>>(x, pbuf);
  k_stats2<<<BATCH, 128, 0, stream>>>(pbuf, stats);
  k_t<<<dim3(32,4,2), 256, 0, stream>>>(x, gn_w, gn_b, stats, t_buf);

  EpiInProj e1{z_buf, xraw, dt_buf, (const float*)d_in[8], (const float*)d_in[16]};
  gemm_epi<EpiInProj><<<dim3(32, 37, 2), 256, 0, stream>>>(
      t_buf, DMODEL, inw_bf, DMODEL, M_TOT, DPROJ, DMODEL, e1);

  k_conv<<<dim3(5, L_SEQ, 2*BATCH), 256, 0, stream>>>(
      xraw, (const float*)d_in[6], (const float*)d_in[7],
            (const float*)d_in[14], (const float*)d_in[15], xconv);
  k_scan<<<2*BATCH*NH*NCHK, 256, 0, stream>>>(
      dt_buf, (const float*)d_in[9], (const float*)d_in[17], acs);
  k_states<<<2*BATCH*NCHK*NH, 256, 0, stream>>>(xconv, dt_buf, acs, states);
  k_recur<<<2*BATCH*NH*32, 256, 0, stream>>>(states, acs);
  k_cb<<<dim3(4,4,2*BATCH*NCHK), 256, 0, stream>>>(xconv, cb);
  k_y_mfma<<<2*BATCH*NCHK*NH*2, 256, 0, stream>>>(xconv, dt_buf, acs, cb, states, y_buf);
  k_gaterms<<<2*M_TOT, 256, 0, stream>>>(
      z_buf, (const float*)d_in[11], (const float*)d_in[19], xconv,
      (const float*)d_in[10], (const float*)d_in[18], y_buf);

  gemm_atomic2<<<dim3(32, 4, 8), 256, 0, stream>>>(
      y_buf, DINNER, outw_bf, DINNER, M_TOT, DMODEL, DINNER, scr);
  post_outproj<<<2*M_TOT/8, 256, 0, stream>>>(scr, t_buf, r_buf);

  gemm_atomic<<<dim3(32, 4, 4), 256, 0, stream>>>(
      r_buf, 2*DMODEL, projw_bf, 2*DMODEL, M_TOT, DMODEL, 2*DMODEL, scr_fin);
  post_final<<<dim3(32, 4, 2), 256, 0, stream>>>(scr_fin, x, proj_b, out);
}

// Round 2
// 305.775 us; speedup vs baseline: 1.3919x; 1.1060x over previous
//
#include <hip/hip_runtime.h>
#include <hip/hip_bf16.h>
#include <math.h>

using bf16 = __hip_bfloat16;

#define L_SEQ   2048
#define DMODEL  256
#define DINNER  1024
#define DSTATE  128
#define NH      16
#define HD      64
#define CONVDIM 1280
#define DPROJ   2320
#define NCHK    8
#define CT      256
#define BATCH   2
#define M_TOT   (BATCH*L_SEQ)

#define ACS_N   (BATCH*NH*NCHK*CT)
#define ST_N    ((size_t)BATCH*NCHK*NH*HD*DSTATE)
#define CB_N    ((size_t)BATCH*NCHK*CT*CT)

typedef __bf16 bf16x8_t __attribute__((ext_vector_type(8)));
typedef __bf16 bf16x4_t __attribute__((ext_vector_type(4)));
typedef float  f32x4_t  __attribute__((ext_vector_type(4)));

__device__ __forceinline__ float tof(bf16 v){ return __bfloat162float(v); }
__device__ __forceinline__ bf16  tob(float v){ return __float2bfloat16(v); }
__device__ __forceinline__ float expdec(float a){ return expf(fminf(a, 0.f)); }

// ---------------- fp32 -> bf16 cast (all weights, one launch) --------------------
struct CastJob  { const float* src; bf16* dst; int n; };
struct CastJobs { CastJob j[5]; };

__global__ __launch_bounds__(256) void k_cast5(CastJobs jobs){
  CastJob jb = jobs.j[blockIdx.y];
  int i = (blockIdx.x*256 + threadIdx.x)*4;
  if (i < jb.n){
    float4 v = *(const float4*)(jb.src + i);
    jb.dst[i]   = tob(v.x); jb.dst[i+1] = tob(v.y);
    jb.dst[i+2] = tob(v.z); jb.dst[i+3] = tob(v.w);
  }
}

// ---------------- batch stats ----------------------------------------------------
__global__ __launch_bounds__(256) void k_stats1(const float* __restrict__ x, float2* __restrict__ pbuf){
  int b = blockIdx.y, blk = blockIdx.x, t = threadIdx.x;
  const float4* p = (const float4*)(x + (size_t)b*(DMODEL*L_SEQ) + (size_t)blk*4096);
  float s = 0.f, ss = 0.f;
  #pragma unroll
  for (int k = 0; k < 4; ++k){
    float4 v = p[t + k*256];
    s  += v.x + v.y + v.z + v.w;
    ss += v.x*v.x + v.y*v.y + v.z*v.z + v.w*v.w;
  }
  for (int o = 32; o > 0; o >>= 1){ s += __shfl_down(s, o, 64); ss += __shfl_down(ss, o, 64); }
  __shared__ float sh[8];
  if ((t & 63) == 0){ sh[(t>>6)*2] = s; sh[(t>>6)*2+1] = ss; }
  __syncthreads();
  if (t == 0){
    s  = sh[0]+sh[2]+sh[4]+sh[6];
    ss = sh[1]+sh[3]+sh[5]+sh[7];
    pbuf[b*128 + blk] = make_float2(s, ss);
  }
}

__global__ __launch_bounds__(128) void k_stats2(const float2* __restrict__ pbuf, float* __restrict__ stats){
  int b = blockIdx.x, t = threadIdx.x;
  float2 v = pbuf[b*128 + t];
  float s = v.x, ss = v.y;
  for (int o = 32; o > 0; o >>= 1){ s += __shfl_down(s, o, 64); ss += __shfl_down(ss, o, 64); }
  __shared__ float sh[4];
  if ((t & 63) == 0){ sh[(t>>6)*2] = s; sh[(t>>6)*2+1] = ss; }
  __syncthreads();
  if (t == 0){
    s  = sh[0]+sh[2];
    ss = sh[1]+sh[3];
    float inv = 1.f/(float)(DMODEL*L_SEQ);
    float mu = s*inv, var = ss*inv - mu*mu;
    stats[0 + b*2] = mu; stats[1 + b*2] = rsqrtf(fmaxf(var, 0.f) + 1.1920929e-07f);
  }
}

// ---------------- GroupNorm + transpose ------------------------------------------
__global__ __launch_bounds__(256) void k_t(const float* __restrict__ x, const float* __restrict__ gw,
                                           const float* __restrict__ gb, const float* __restrict__ stats,
                                           bf16* __restrict__ t_out){
  __shared__ float tile[64][65];
  int l0 = blockIdx.x*64, c0 = blockIdx.y*64, b = blockIdx.z;
  float mu = stats[b*2], istd = stats[b*2+1];
  int tid = threadIdx.x;
  int lx = tid & 63, cy = tid >> 6;
  for (int cc = cy; cc < 64; cc += 4){
    float v = x[(size_t)b*DMODEL*L_SEQ + (size_t)(c0+cc)*L_SEQ + l0+lx];
    tile[cc][lx] = (v - mu)*istd;
  }
  __syncthreads();
  int cx = tid & 63, ly = tid >> 6;
  float w = gw[c0+cx], bb = gb[c0+cx];
  for (int ll = ly; ll < 64; ll += 4)
    t_out[((size_t)(b*L_SEQ) + l0+ll)*DMODEL + c0+cx] = tob(tile[cx][ll]*w + bb);
}

// ---------------- MFMA GEMM 128x64, dir-batched (z), direct epilogue -------------
template<class Epi>
__global__ __launch_bounds__(256) void gemm_epi(const bf16* __restrict__ A, int lda,
                                                const bf16* __restrict__ B, int ldb,
                                                int M, int N, int K, Epi epi){
  __shared__ __align__(16) bf16 lds[2][(128+64)*40];
  int dir = blockIdx.z;
  const bf16* Bd = B + (size_t)dir*(size_t)N*ldb;
  int m0 = blockIdx.x*128, n0 = blockIdx.y*64;
  int t = threadIdx.x;
  int wave = t >> 6, lane = t & 63;
  int wm = (wave & 1)*64, wn = (wave >> 1)*32;
  int lrow = lane & 15, quad = lane >> 4, lk8 = quad*8;

  int r0 = t >> 2, o0 = (t & 3)*8;
  int r1 = r0 + 64;
  int am0 = m0 + r0, am1 = m0 + r1;
  if (dir){
    am0 = (am0 & ~(L_SEQ-1)) | ((L_SEQ-1) - (am0 & (L_SEQ-1)));
    am1 = (am1 & ~(L_SEQ-1)) | ((L_SEQ-1) - (am1 & (L_SEQ-1)));
  }
  int bn = n0 + r0; if (bn > N-1) bn = N-1;
  const bf16* Ap0 = A + (size_t)am0*lda + o0;
  const bf16* Ap1 = A + (size_t)am1*lda + o0;
  const bf16* Bp  = Bd + (size_t)bn*ldb + o0;

  f32x4_t acc[4][2];
  #pragma unroll
  for (int i = 0; i < 4; ++i){ acc[i][0] = (f32x4_t){0,0,0,0}; acc[i][1] = (f32x4_t){0,0,0,0}; }

  int nit = K >> 5;
  uint4 a0 = *(const uint4*)Ap0;
  uint4 a1 = *(const uint4*)Ap1;
  uint4 b0 = *(const uint4*)Bp;
  int st = 0;
  *(uint4*)&lds[0][r0*40 + o0] = a0;
  *(uint4*)&lds[0][r1*40 + o0] = a1;
  *(uint4*)&lds[0][(128 + r0)*40 + o0] = b0;
  __syncthreads();
  for (int it = 0; it < nit; ++it){
    bool more = (it+1 < nit);
    if (more){
      int kk = (it+1) << 5;
      a0 = *(const uint4*)(Ap0 + kk);
      a1 = *(const uint4*)(Ap1 + kk);
      b0 = *(const uint4*)(Bp + kk);
    }
    const bf16* cs = lds[st];
    bf16x8_t af[4], bfr[2];
    #pragma unroll
    for (int mi = 0; mi < 4; ++mi) af[mi] = *(const bf16x8_t*)&cs[(wm + mi*16 + lrow)*40 + lk8];
    #pragma unroll
    for (int ni = 0; ni < 2; ++ni) bfr[ni] = *(const bf16x8_t*)&cs[(128 + wn + ni*16 + lrow)*40 + lk8];
    #pragma unroll
    for (int mi = 0; mi < 4; ++mi)
      #pragma unroll
      for (int ni = 0; ni < 2; ++ni)
        acc[mi][ni] = __builtin_amdgcn_mfma_f32_16x16x32_bf16(af[mi], bfr[ni], acc[mi][ni], 0, 0, 0);
    if (more){
      st ^= 1;
      *(uint4*)&lds[st][r0*40 + o0] = a0;
      *(uint4*)&lds[st][r1*40 + o0] = a1;
      *(uint4*)&lds[st][(128 + r0)*40 + o0] = b0;
      __syncthreads();
    }
  }
  #pragma unroll
  for (int mi = 0; mi < 4; ++mi)
    #pragma unroll
    for (int ni = 0; ni < 2; ++ni)
      #pragma unroll
      for (int r = 0; r < 4; ++r){
        int m = m0 + wm + mi*16 + quad*4 + r;
        int n = n0 + wn + ni*16 + lrow;
        if (m < M && n < N) epi(dir, m, n, acc[mi][ni][r]);
      }
}

// ---------------- MFMA GEMM 128x64, split-K + dir (grid.z), fp32 atomic ---------
__global__ __launch_bounds__(256) void gemm_atomic2(const bf16* __restrict__ A, int lda,
                                                    const bf16* __restrict__ B, int ldb,
                                                    int M, int N, int K, float* __restrict__ scr){
  __shared__ __align__(16) bf16 lds[2][(128+64)*40];
  int zz = blockIdx.z; int dir = zz & 1; int kz = zz >> 1;
  const bf16* Ad = A + (size_t)dir*(size_t)M_TOT*DINNER;
  const bf16* Bd = B + (size_t)dir*(size_t)DMODEL*DINNER;
  float* sd = scr + (size_t)dir*(size_t)M_TOT*DMODEL;
  int m0 = blockIdx.x*128, n0 = blockIdx.y*64;
  int kc = K >> 2;
  int ks = kz * kc;
  int t = threadIdx.x;
  int wave = t >> 6, lane = t & 63;
  int wm = (wave & 1)*64, wn = (wave >> 1)*32;
  int lrow = lane & 15, quad = lane >> 4, lk8 = quad*8;

  int r0 = t >> 2, o0 = (t & 3)*8;
  int r1 = r0 + 64;
  const bf16* Ap0 = Ad + (size_t)(m0 + r0)*lda + ks + o0;
  const bf16* Ap1 = Ad + (size_t)(m0 + r1)*lda + ks + o0;
  const bf16* Bp  = Bd + (size_t)(n0 + r0)*ldb + ks + o0;

  f32x4_t acc[4][2];
  #pragma unroll
  for (int i = 0; i < 4; ++i){ acc[i][0] = (f32x4_t){0,0,0,0}; acc[i][1] = (f32x4_t){0,0,0,0}; }

  int nit = kc >> 5;
  uint4 a0 = *(const uint4*)Ap0;
  uint4 a1 = *(const uint4*)Ap1;
  uint4 b0 = *(const uint4*)Bp;
  int st = 0;
  *(uint4*)&lds[0][r0*40 + o0] = a0;
  *(uint4*)&lds[0][r1*40 + o0] = a1;
  *(uint4*)&lds[0][(128 + r0)*40 + o0] = b0;
  __syncthreads();
  for (int it = 0; it < nit; ++it){
    bool more = (it+1 < nit);
    if (more){
      int kk = (it+1) << 5;
      a0 = *(const uint4*)(Ap0 + kk);
      a1 = *(const uint4*)(Ap1 + kk);
      b0 = *(const uint4*)(Bp + kk);
    }
    const bf16* cs = lds[st];
    bf16x8_t af[4], bfr[2];
    #pragma unroll
    for (int mi = 0; mi < 4; ++mi) af[mi] = *(const bf16x8_t*)&cs[(wm + mi*16 + lrow)*40 + lk8];
    #pragma unroll
    for (int ni = 0; ni < 2; ++ni) bfr[ni] = *(const bf16x8_t*)&cs[(128 + wn + ni*16 + lrow)*40 + lk8];
    #pragma unroll
    for (int mi = 0; mi < 4; ++mi)
      #pragma unroll
      for (int ni = 0; ni < 2; ++ni)
        acc[mi][ni] = __builtin_amdgcn_mfma_f32_16x16x32_bf16(af[mi], bfr[ni], acc[mi][ni], 0, 0, 0);
    if (more){
      st ^= 1;
      *(uint4*)&lds[st][r0*40 + o0] = a0;
      *(uint4*)&lds[st][r1*40 + o0] = a1;
      *(uint4*)&lds[st][(128 + r0)*40 + o0] = b0;
      __syncthreads();
    }
  }
  #pragma unroll
  for (int mi = 0; mi < 4; ++mi)
    #pragma unroll
    for (int ni = 0; ni < 2; ++ni)
      #pragma unroll
      for (int r = 0; r < 4; ++r){
        int m = m0 + wm + mi*16 + quad*4 + r;
        int n = n0 + wn + ni*16 + lrow;
        atomicAdd(&sd[(size_t)m*N + n], acc[mi][ni][r]);
      }
}

// ---------------- plain split-K atomic GEMM (final projection) -------------------
__global__ __launch_bounds__(256) void gemm_atomic(const bf16* __restrict__ A, int lda,
                                                   const bf16* __restrict__ B, int ldb,
                                                   int M, int N, int K, float* __restrict__ scr){
  __shared__ __align__(16) bf16 lds[2][(128+64)*40];
  int m0 = blockIdx.x*128, n0 = blockIdx.y*64;
  int kc = K / gridDim.z;
  int ks = blockIdx.z * kc;
  int t = threadIdx.x;
  int wave = t >> 6, lane = t & 63;
  int wm = (wave & 1)*64, wn = (wave >> 1)*32;
  int lrow = lane & 15, quad = lane >> 4, lk8 = quad*8;

  int r0 = t >> 2, o0 = (t & 3)*8;
  int r1 = r0 + 64;
  const bf16* Ap0 = A + (size_t)(m0 + r0)*lda + ks + o0;
  const bf16* Ap1 = A + (size_t)(m0 + r1)*lda + ks + o0;
  const bf16* Bp  = B + (size_t)(n0 + r0)*ldb + ks + o0;

  f32x4_t acc[4][2];
  #pragma unroll
  for (int i = 0; i < 4; ++i){ acc[i][0] = (f32x4_t){0,0,0,0}; acc[i][1] = (f32x4_t){0,0,0,0}; }

  int nit = kc >> 5;
  uint4 a0 = *(const uint4*)Ap0;
  uint4 a1 = *(const uint4*)Ap1;
  uint4 b0 = *(const uint4*)Bp;
  int st = 0;
  *(uint4*)&lds[0][r0*40 + o0] = a0;
  *(uint4*)&lds[0][r1*40 + o0] = a1;
  *(uint4*)&lds[0][(128 + r0)*40 + o0] = b0;
  __syncthreads();
  for (int it = 0; it < nit; ++it){
    bool more = (it+1 < nit);
    if (more){
      int kk = (it+1) << 5;
      a0 = *(const uint4*)(Ap0 + kk);
      a1 = *(const uint4*)(Ap1 + kk);
      b0 = *(const uint4*)(Bp + kk);
    }
    const bf16* cs = lds[st];
    bf16x8_t af[4], bfr[2];
    #pragma unroll
    for (int mi = 0; mi < 4; ++mi) af[mi] = *(const bf16x8_t*)&cs[(wm + mi*16 + lrow)*40 + lk8];
    #pragma unroll
    for (int ni = 0; ni < 2; ++ni) bfr[ni] = *(const bf16x8_t*)&cs[(128 + wn + ni*16 + lrow)*40 + lk8];
    #pragma unroll
    for (int mi = 0; mi < 4; ++mi)
      #pragma unroll
      for (int ni = 0; ni < 2; ++ni)
        acc[mi][ni] = __builtin_amdgcn_mfma_f32_16x16x32_bf16(af[mi], bfr[ni], acc[mi][ni], 0, 0, 0);
    if (more){
      st ^= 1;
      *(uint4*)&lds[st][r0*40 + o0] = a0;
      *(uint4*)&lds[st][r1*40 + o0] = a1;
      *(uint4*)&lds[st][(128 + r0)*40 + o0] = b0;
      __syncthreads();
    }
  }
  #pragma unroll
  for (int mi = 0; mi < 4; ++mi)
    #pragma unroll
    for (int ni = 0; ni < 2; ++ni)
      #pragma unroll
      for (int r = 0; r < 4; ++r){
        int m = m0 + wm + mi*16 + quad*4 + r;
        int n = n0 + wn + ni*16 + lrow;
        atomicAdd(&scr[(size_t)m*N + n], acc[mi][ni][r]);
      }
}

struct EpiInProj {
  bf16* z; bf16* xbc; float* dt; const float* db0; const float* db1;
  __device__ void operator()(int dir, int m, int n, float v) const {
    size_t mm = (size_t)dir*M_TOT + m;
    if (n < DINNER) z[mm*DINNER + n] = tob(v);
    else if (n < DINNER+CONVDIM) xbc[mm*CONVDIM + (n-DINNER)] = tob(v);
    else {
      int h = n - (DINNER+CONVDIM);
      float xx = v + (dir ? db1 : db0)[h];
      dt[mm*NH + h] = (xx > 20.f) ? xx : log1pf(expf(xx));
    }
  }
};

// ---------------- post: out-proj epilogue (scr + t -> r, dir-batched) ------------
__global__ __launch_bounds__(256) void post_outproj(const float* __restrict__ scr, const bf16* __restrict__ tb,
                                                    bf16* __restrict__ r){
  int n = threadIdx.x;
  int zb = blockIdx.x;
  int dir = zb >> 9; int mb = (zb & 511)*8;
  const float* sd = scr + (size_t)dir*(size_t)M_TOT*DMODEL;
  for (int i = 0; i < 8; ++i){
    int mm = mb + i;
    int pm = dir ? ((mm & ~(L_SEQ-1)) | ((L_SEQ-1) - (mm & (L_SEQ-1)))) : mm;
    r[(size_t)pm*(2*DMODEL) + dir*DMODEL + n] = tob(sd[(size_t)mm*DMODEL + n] + tof(tb[(size_t)pm*DMODEL + n]));
  }
}

// ---------------- post: final epilogue (scr + pb + x -> out, transposed) ---------
__global__ __launch_bounds__(256) void post_final(const float* __restrict__ scr, const float* __restrict__ x,
                                                  const float* __restrict__ pb, float* __restrict__ out){
  __shared__ float tile[64][65];
  int l0 = blockIdx.x*64, n0 = blockIdx.y*64, b = blockIdx.z;
  int tid = threadIdx.x;
  int nx = tid & 63, ly = tid >> 6;
  for (int ll = ly; ll < 64; ll += 4)
    tile[ll][nx] = scr[((size_t)(b*L_SEQ) + l0+ll)*DMODEL + n0+nx];
  __syncthreads();
  int lx = tid & 63, ny = tid >> 6;
  for (int nn = ny; nn < 64; nn += 4){
    int n = n0 + nn;
    size_t xi = (size_t)b*DMODEL*L_SEQ + (size_t)n*L_SEQ + l0+lx;
    out[xi] = tile[lx][nn] + pb[n] + x[xi];
  }
}

// ---------------- depthwise causal conv + SiLU, vectorized rolling window --------
// block: 256 thr = 32 chgroups(x8ch) * 8 lrows(x4 l). grid: (5, L_SEQ/32, 2*BATCH)
__global__ __launch_bounds__(256) void k_conv(const bf16* __restrict__ xraw, const float* __restrict__ cw0,
                                              const float* __restrict__ cb0, const float* __restrict__ cw1,
                                              const float* __restrict__ cb1, bf16* __restrict__ xconv){
  int t = threadIdx.x;
  int tx = t & 31, ty = t >> 5;
  int ch0 = blockIdx.x*256 + tx*8;
  int z = blockIdx.z; int b = z & 1, dir = z >> 1;
  int lbase = blockIdx.y*32 + ty*4;
  const float* cw = dir ? cw1 : cw0;
  const float* cb = dir ? cb1 : cb0;
  const bf16* xr = xraw  + (size_t)dir*((size_t)M_TOT*CONVDIM) + (size_t)(b*L_SEQ)*CONVDIM + ch0;
  bf16* xcv      = xconv + (size_t)dir*((size_t)M_TOT*CONVDIM) + (size_t)(b*L_SEQ)*CONVDIM + ch0;

  float wk[4][8];
  #pragma unroll
  for (int c = 0; c < 8; ++c){
    float4 w = *(const float4*)&cw[(ch0+c)*4];
    wk[0][c] = w.x; wk[1][c] = w.y; wk[2][c] = w.z; wk[3][c] = w.w;
  }
  float bias[8];
  {
    float4 b0v = *(const float4*)&cb[ch0];
    float4 b1v = *(const float4*)&cb[ch0+4];
    bias[0]=b0v.x; bias[1]=b0v.y; bias[2]=b0v.z; bias[3]=b0v.w;
    bias[4]=b1v.x; bias[5]=b1v.y; bias[6]=b1v.z; bias[7]=b1v.w;
  }

  bf16x8_t zero;
  #pragma unroll
  for (int c = 0; c < 8; ++c) zero[c] = (__bf16)0.f;

  bf16x8_t win[4];
  #pragma unroll
  for (int k = 0; k < 3; ++k){
    int ls = lbase - 3 + k;
    win[k] = (ls >= 0) ? *(const bf16x8_t*)&xr[(size_t)ls*CONVDIM] : zero;
  }
  #pragma unroll
  for (int i = 0; i < 4; ++i){
    int l = lbase + i;
    win[3] = *(const bf16x8_t*)&xr[(size_t)l*CONVDIM];
    bf16x8_t outv;
    #pragma unroll
    for (int c = 0; c < 8; ++c){
      float a = bias[c] + (float)win[0][c]*wk[0][c] + (float)win[1][c]*wk[1][c]
                        + (float)win[2][c]*wk[2][c] + (float)win[3][c]*wk[3][c];
      outv[c] = (__bf16)(a / (1.f + expf(-a)));
    }
    *(bf16x8_t*)&xcv[(size_t)l*CONVDIM] = outv;
    win[0] = win[1]; win[1] = win[2]; win[2] = win[3];
  }
}

// ---------------- per-(dir,b,h,chunk) inclusive cumsum of A ----------------------
__global__ __launch_bounds__(256) void k_scan(const float* __restrict__ dt, const float* __restrict__ Al0,
                                              const float* __restrict__ Al1, float* __restrict__ A_cs){
  int id0 = blockIdx.x;
  int dir = id0 >> 8; int id = id0 & 255;
  int ch = id & 7; int bh = id >> 3; int h = bh & 15; int b = bh >> 4;
  const float* Alog = dir ? Al1 : Al0;
  const float* dtp = dt + (size_t)dir*((size_t)M_TOT*NH);
  float* acsd = A_cs + (size_t)dir*ACS_N;
  int l = threadIdx.x;
  int gl = ch*CT + l;
  float a = -expf(Alog[h]) * dtp[((size_t)(b*L_SEQ)+gl)*NH + h];
  __shared__ float s[256];
  s[l] = a; __syncthreads();
  for (int off = 1; off < 256; off <<= 1){
    float v = (l >= off) ? s[l-off] : 0.f;
    __syncthreads();
    s[l] += v;
    __syncthreads();
  }
  acsd[(size_t)id*CT + l] = s[l];
}

// ---------------- per-chunk states (vectorized staging, dir-batched) -------------
__global__ __launch_bounds__(256) void k_states(const bf16* __restrict__ xconv, const float* __restrict__ dt,
                                                const float* __restrict__ A_cs, float* __restrict__ states){
  int id0 = blockIdx.x;
  int dir = id0 >> 8; int id = id0 & 255;
  int h = id & 15; int bc = id >> 4; int ch = bc & 7; int b = bc >> 3;
  int t = threadIdx.x;
  __shared__ float w_s[64];
  __shared__ __align__(16) float Xs[64*64];
  __shared__ __align__(16) float Bs[64*128];
  const bf16* xc = xconv + (size_t)dir*((size_t)M_TOT*CONVDIM);
  const float* dtp = dt + (size_t)dir*((size_t)M_TOT*NH);
  const float* acs = A_cs + (size_t)dir*ACS_N + (size_t)((b*NH+h)*NCHK + ch)*CT;
  float alast = acs[CT-1];
  float acc[4][8] = {};
  int tx = t & 15, ty = t >> 4;
  size_t rowbase = (size_t)(b*L_SEQ) + ch*CT;
  for (int lt = 0; lt < 4; ++lt){
    int lbase = lt*64;
    if (t < 64)
      w_s[t] = dtp[(rowbase + lbase + t)*NH + h] * expdec(alast - acs[lbase + t]);
    __syncthreads();
    #pragma unroll
    for (int it = 0; it < 2; ++it){
      int idx = t + it*256; int l = idx >> 3; int p0 = (idx & 7)*8;
      bf16x8_t v = *(const bf16x8_t*)&xc[(rowbase + lbase + l)*CONVDIM + h*HD + p0];
      float w = w_s[l];
      float4 f0 = { (float)v[0]*w, (float)v[1]*w, (float)v[2]*w, (float)v[3]*w };
      float4 f1 = { (float)v[4]*w, (float)v[5]*w, (float)v[6]*w, (float)v[7]*w };
      *(float4*)&Xs[l*64 + p0]     = f0;
      *(float4*)&Xs[l*64 + p0 + 4] = f1;
    }
    #pragma unroll
    for (int it = 0; it < 4; ++it){
      int idx = t + it*256; int l = idx >> 4; int n0 = (idx & 15)*8;
      bf16x8_t v = *(const bf16x8_t*)&xc[(rowbase + lbase + l)*CONVDIM + DINNER + n0];
      float4 f0 = { (float)v[0], (float)v[1], (float)v[2], (float)v[3] };
      float4 f1 = { (float)v[4], (float)v[5], (float)v[6], (float)v[7] };
      *(float4*)&Bs[l*128 + n0]     = f0;
      *(float4*)&Bs[l*128 + n0 + 4] = f1;
    }
    __syncthreads();
    for (int l = 0; l < 64; ++l){
      float4 pv = *(const float4*)&Xs[l*64 + ty*4];
      float4 na = *(const float4*)&Bs[l*128 + tx*8];
      float4 nb = *(const float4*)&Bs[l*128 + tx*8 + 4];
      float pr[4] = {pv.x, pv.y, pv.z, pv.w};
      float nr[8] = {na.x, na.y, na.z, na.w, nb.x, nb.y, nb.z, nb.w};
      #pragma unroll
      for (int i = 0; i < 4; ++i)
        #pragma unroll
        for (int j = 0; j < 8; ++j) acc[i][j] += pr[i]*nr[j];
    }
    __syncthreads();
  }
  float* so = states + (size_t)dir*ST_N + (size_t)id*HD*DSTATE;
  #pragma unroll
  for (int i = 0; i < 4; ++i)
    #pragma unroll
    for (int j = 0; j < 8; ++j)
      so[(ty*4+i)*DSTATE + tx*8+j] = acc[i][j];
}

// ---------------- inter-chunk recurrence (one element per thread) ----------------
__global__ __launch_bounds__(256) void k_recur(float* __restrict__ states, const float* __restrict__ A_cs){
  int blk = blockIdx.x;                 // [0, 2048): (dir,b,h) x 32 blocks
  int bh2 = blk >> 5;
  int e = (blk & 31)*256 + threadIdx.x; // [0, HD*DSTATE)
  int dir = bh2 >> 5; int bh = bh2 & 31;
  int h = bh & 15, b = bh >> 4;
  const float* ac = A_cs + (size_t)dir*ACS_N;
  float* st = states + (size_t)dir*ST_N;
  float s = 0.f;
  #pragma unroll
  for (int ch = 0; ch < NCHK; ++ch){
    float dec = expdec(ac[((size_t)(bh*NCHK+ch))*CT + CT-1]);
    size_t off = (size_t)(((b*NCHK+ch)*NH)+h)*HD*DSTATE + e;
    float cur = st[off];
    st[off] = s;
    s = s*dec + cur;
  }
}

// ---------------- CB = C · B^T per (dir,b,chunk) ---------------------------------
__global__ __launch_bounds__(256) void k_cb(const bf16* __restrict__ xconv, float* __restrict__ CB){
  int zz = blockIdx.z;
  int dir = zz >> 4; int b = (zz >> 3) & 1; int ch = zz & 7;
  int m0 = blockIdx.x*64, n0 = blockIdx.y*64;
  if (n0 > m0 + 63) return;
  const bf16* base = xconv + (size_t)dir*((size_t)M_TOT*CONVDIM) + (size_t)(b*L_SEQ + ch*CT)*CONVDIM;
  const bf16* Crow = base + DINNER + DSTATE;
  const bf16* Brow = base + DINNER;
  __shared__ __align__(16) float As[16][68];
  __shared__ __align__(16) float Bs[16][68];
  int t = threadIdx.x, tx = t & 15, ty = t >> 4;
  float acc[4][4] = {};
  int lr = t >> 2, lk = (t & 3)*4;
  for (int k0 = 0; k0 < DSTATE; k0 += 16){
    #pragma unroll
    for (int j = 0; j < 4; ++j) As[lk+j][lr] = tof(Crow[(size_t)(m0+lr)*CONVDIM + k0+lk+j]);
    #pragma unroll
    for (int j = 0; j < 4; ++j) Bs[lk+j][lr] = tof(Brow[(size_t)(n0+lr)*CONVDIM + k0+lk+j]);
    __syncthreads();
    #pragma unroll
    for (int kk = 0; kk < 16; ++kk){
      float4 av = *(const float4*)&As[kk][ty*4];
      float4 bv = *(const float4*)&Bs[kk][tx*4];
      acc[0][0] += av.x*bv.x; acc[0][1] += av.x*bv.y; acc[0][2] += av.x*bv.z; acc[0][3] += av.x*bv.w;
      acc[1][0] += av.y*bv.x; acc[1][1] += av.y*bv.y; acc[1][2] += av.y*bv.z; acc[1][3] += av.y*bv.w;
      acc[2][0] += av.z*bv.x; acc[2][1] += av.z*bv.y; acc[2][2] += av.z*bv.z; acc[2][3] += av.z*bv.w;
      acc[3][0] += av.w*bv.x; acc[3][1] += av.w*bv.y; acc[3][2] += av.w*bv.z; acc[3][3] += av.w*bv.w;
    }
    __syncthreads();
  }
  float* outp = CB + (size_t)dir*CB_N + (size_t)(b*NCHK+ch)*CT*CT;
  #pragma unroll
  for (int i = 0; i < 4; ++i)
    #pragma unroll
    for (int j = 0; j < 4; ++j)
      outp[(m0+ty*4+i)*CT + n0+tx*4+j] = acc[i][j];
}

// ---------------- Y = (L*CB)@X + exp(Acs)*(C@NS)  (MFMA, dir-batched) ------------
__global__ __launch_bounds__(256) void k_y_mfma(const bf16* __restrict__ xconv, const float* __restrict__ dt,
                                                const float* __restrict__ A_cs, const float* __restrict__ CB,
                                                const float* __restrict__ ns, bf16* __restrict__ y){
  int id0 = blockIdx.x;
  int dir = id0 >> 9; int id = id0 & 511;
  int hh = id & 1; int r = id >> 1; int h = r & 15; int bc = r >> 4; int ch = bc & 7; int b = bc >> 3;
  int t = threadIdx.x;
  int lane = t & 63;
  int lrow = lane & 15, quad = lane >> 4;

  __shared__ __align__(16) bf16 Xs[64*264];
  __shared__ __align__(16) bf16 NSs[64*136];
  __shared__ float acs_s[CT];

  const bf16* xc = xconv + (size_t)dir*((size_t)M_TOT*CONVDIM);
  const float* dtp = dt + (size_t)dir*((size_t)M_TOT*NH);
  const float* acs = A_cs + (size_t)dir*ACS_N + (size_t)((b*NH+h)*NCHK + ch)*CT;
  const float* cbz = CB + (size_t)dir*CB_N + (size_t)(b*NCHK+ch)*CT*CT;
  const float* nsp = ns + (size_t)dir*ST_N + (size_t)(((b*NCHK+ch)*NH)+h)*HD*DSTATE;
  bf16* yp = y + (size_t)dir*((size_t)M_TOT*DINNER);
  size_t rowbase = (size_t)(b*L_SEQ + ch*CT);
  acs_s[t] = acs[t];

  // X staging: vectorized bf16x8 loads, scatter into [p][s] layout
  #pragma unroll
  for (int it = 0; it < 8; ++it){
    int idx = t + it*256;
    int s = idx >> 3, p0 = (idx & 7)*8;
    float dtv = dtp[(rowbase + s)*NH + h];
    bf16x8_t v = *(const bf16x8_t*)&xc[(rowbase + s)*CONVDIM + h*HD + p0];
    #pragma unroll
    for (int j = 0; j < 8; ++j)
      Xs[(p0+j)*264 + s] = tob((float)v[j] * dtv);
  }
  for (int it = 0; it < 8; ++it){
    int idx = t + it*256;
    int n4 = (idx & 31)*4, p = idx >> 5;
    float4 v = *(const float4*)(nsp + p*DSTATE + n4);
    bf16* w = &NSs[p*136 + n4];
    w[0] = tob(v.x); w[1] = tob(v.y); w[2] = tob(v.z); w[3] = tob(v.w);
  }
  __syncthreads();

  int wave = t >> 6;
  int row0 = hh*128 + wave*32;
  float al0 = acs_s[row0 + lrow];
  float al1 = acs_s[row0 + 16 + lrow];
  float acs_r0 = acs_s[row0];

  f32x4_t acc[2][4];
  #pragma unroll
  for (int i = 0; i < 2; ++i)
    #pragma unroll
    for (int j = 0; j < 4; ++j) acc[i][j] = (f32x4_t){0.f,0.f,0.f,0.f};

  int nst = (row0 + 32) >> 5;
  for (int st = 0; st < nst; ++st){
    int s0 = st*32;
    if (s0 + 31 < row0 && (acs_r0 - acs_s[s0+31]) < -30.f) continue;
    bf16x8_t bq[4];
    #pragma unroll
    for (int nt = 0; nt < 4; ++nt)
      bq[nt] = *(const bf16x8_t*)&Xs[(nt*16+lrow)*264 + s0 + quad*8];
    bf16x8_t af[2];
    #pragma unroll
    for (int mt = 0; mt < 2; ++mt){
      int l = row0 + mt*16 + lrow;
      float al = mt ? al1 : al0;
      const float* cbrow = cbz + (size_t)l*CT + s0 + quad*8;
      float4 c0 = *(const float4*)cbrow;
      float4 c1 = *(const float4*)(cbrow + 4);
      float cv[8] = {c0.x,c0.y,c0.z,c0.w,c1.x,c1.y,c1.z,c1.w};
      union { bf16x8_t v; __bf16 e[8]; } wa;
      #pragma unroll
      for (int j = 0; j < 8; ++j){
        int s = s0 + quad*8 + j;
        float w = (s <= l) ? expf(fminf(al - acs_s[s], 0.f)) * cv[j] : 0.f;
        wa.e[j] = (__bf16)w;
      }
      af[mt] = wa.v;
    }
    #pragma unroll
    for (int mt = 0; mt < 2; ++mt)
      #pragma unroll
      for (int nt = 0; nt < 4; ++nt)
        acc[mt][nt] = __builtin_amdgcn_mfma_f32_16x16x32_bf16(af[mt], bq[nt], acc[mt][nt], 0, 0, 0);
  }

  float el0 = expf(fminf(al0, 0.f));
  float el1 = expf(fminf(al1, 0.f));
  #pragma unroll
  for (int kt = 0; kt < 4; ++kt){
    int n0 = kt*32;
    bf16x8_t bq[4];
    #pragma unroll
    for (int nt = 0; nt < 4; ++nt)
      bq[nt] = *(const bf16x8_t*)&NSs[(nt*16+lrow)*136 + n0 + quad*8];
    bf16x8_t af[2];
    #pragma unroll
    for (int mt = 0; mt < 2; ++mt){
      int l = row0 + mt*16 + lrow;
      float el = mt ? el1 : el0;
      union { bf16x8_t v; __bf16 e[8]; } cu;
      cu.v = *(const bf16x8_t*)&xc[(rowbase + l)*CONVDIM + DINNER + DSTATE + n0 + quad*8];
      union { bf16x8_t v; __bf16 e[8]; } wa;
      #pragma unroll
      for (int j = 0; j < 8; ++j) wa.e[j] = (__bf16)((float)cu.e[j] * el);
      af[mt] = wa.v;
    }
    #pragma unroll
    for (int mt = 0; mt < 2; ++mt)
      #pragma unroll
      for (int nt = 0; nt < 4; ++nt)
        acc[mt][nt] = __builtin_amdgcn_mfma_f32_16x16x32_bf16(af[mt], bq[nt], acc[mt][nt], 0, 0, 0);
  }

  #pragma unroll
  for (int mt = 0; mt < 2; ++mt)
    #pragma unroll
    for (int nt = 0; nt < 4; ++nt)
      #pragma unroll
      for (int rr = 0; rr < 4; ++rr){
        int l = row0 + mt*16 + quad*4 + rr;
        int p = nt*16 + lrow;
        yp[(rowbase + l)*DINNER + h*HD + p] = tob(acc[mt][nt][rr]);
      }
}

// ---------------- gate ((y + D*x) * silu(z)) + RMSNorm, vectorized ---------------
__global__ __launch_bounds__(256) void k_gaterms(const bf16* __restrict__ z, const float* __restrict__ nw0,
                                                 const float* __restrict__ nw1, const bf16* __restrict__ xconv,
                                                 const float* __restrict__ Dh0, const float* __restrict__ Dh1,
                                                 bf16* __restrict__ y){
  int m0 = blockIdx.x;
  int dir = m0 >> 12; int m = m0 & (M_TOT-1);
  int t = threadIdx.x;
  const float* nw = dir ? nw1 : nw0;
  const float* Dh = dir ? Dh1 : Dh0;
  int j0 = t*4;
  const bf16* zp = z + (size_t)dir*((size_t)M_TOT*DINNER) + (size_t)m*DINNER;
  const bf16* xc = xconv + (size_t)dir*((size_t)M_TOT*CONVDIM) + (size_t)m*CONVDIM;
  bf16* yp = y + (size_t)dir*((size_t)M_TOT*DINNER) + (size_t)m*DINNER;

  bf16x4_t zv = *(const bf16x4_t*)&zp[j0];
  bf16x4_t yv = *(const bf16x4_t*)&yp[j0];
  bf16x4_t xv = *(const bf16x4_t*)&xc[j0];
  float Dv = Dh[j0 >> 6];
  float v[4]; float ss = 0.f;
  #pragma unroll
  for (int c = 0; c < 4; ++c){
    float zf = (float)zv[c];
    float raw = (float)yv[c] + Dv*(float)xv[c];
    float g = raw * (zf / (1.f + expf(-zf)));
    v[c] = g; ss += g*g;
  }
  for (int o = 32; o > 0; o >>= 1) ss += __shfl_down(ss, o, 64);
  __shared__ float sh[4];
  if ((t & 63) == 0) sh[t>>6] = ss;
  __syncthreads();
  ss = sh[0]+sh[1]+sh[2]+sh[3];
  float scale = rsqrtf(ss*(1.f/DINNER) + 1e-5f);
  float4 nwv = *(const float4*)&nw[j0];
  float nws[4] = {nwv.x, nwv.y, nwv.z, nwv.w};
  bf16x4_t o;
  #pragma unroll
  for (int c = 0; c < 4; ++c) o[c] = (__bf16)(v[c]*scale*nws[c]);
  *(bf16x4_t*)&yp[j0] = o;
}

extern "C" void kernel_launch(void* const* d_in, const int* in_sizes, int n_in,
                              void* d_out, int out_size, void* d_ws, size_t ws_size,
                              hipStream_t stream){
  (void)in_sizes; (void)n_in; (void)out_size; (void)ws_size;
  const float* x      = (const float*)d_in[0];
  const float* gn_w   = (const float*)d_in[1];
  const float* gn_b   = (const float*)d_in[2];
  const float* proj_w = (const float*)d_in[3];
  const float* proj_b = (const float*)d_in[4];
  float* out = (float*)d_out;

  char* wp = (char*)d_ws;
  auto alloc = [&](size_t bytes){ void* r = (void*)wp; wp += (bytes + 255) & ~(size_t)255; return r; };
  bf16*  t_buf  = (bf16*) alloc((size_t)M_TOT*DMODEL*2);
  bf16*  z_buf  = (bf16*) alloc((size_t)2*M_TOT*DINNER*2);
  bf16*  xraw   = (bf16*) alloc((size_t)2*M_TOT*CONVDIM*2);   // also reused as y (both dirs)
  bf16*  xconv  = (bf16*) alloc((size_t)2*M_TOT*CONVDIM*2);
  float* dt_buf = (float*)alloc((size_t)2*M_TOT*NH*4);
  float* acs    = (float*)alloc((size_t)2*ACS_N*4);
  float* states = (float*)alloc((size_t)2*ST_N*4);
  float* cb     = (float*)alloc((size_t)2*CB_N*4);
  bf16*  r_buf  = (bf16*) alloc((size_t)M_TOT*2*DMODEL*2);
  float* stats  = (float*)alloc(16);
  float2* pbuf  = (float2*)alloc(BATCH*128*sizeof(float2));
  bf16*  inw_bf   = (bf16*)alloc((size_t)2*DPROJ*DMODEL*2);
  bf16*  outw_bf  = (bf16*)alloc((size_t)2*DMODEL*DINNER*2);
  bf16*  projw_bf = (bf16*)alloc((size_t)DMODEL*2*DMODEL*2);
  float* scr      = (float*)alloc((size_t)3*M_TOT*DMODEL*4);   // [dir0][dir1][final]
  float* scr_fin  = scr + (size_t)2*M_TOT*DMODEL;
  bf16*  y_buf    = xraw;   // xraw dead after conv; y indexed (dir*M_TOT+m)*DINNER fits inside

  hipMemsetAsync(scr, 0, (size_t)3*M_TOT*DMODEL*4, stream);

  CastJobs jobs;
  jobs.j[0] = { (const float*)d_in[5],  inw_bf,                              DPROJ*DMODEL };
  jobs.j[1] = { (const float*)d_in[13], inw_bf + (size_t)DPROJ*DMODEL,       DPROJ*DMODEL };
  jobs.j[2] = { (const float*)d_in[12], outw_bf,                             DMODEL*DINNER };
  jobs.j[3] = { (const float*)d_in[20], outw_bf + (size_t)DMODEL*DINNER,     DMODEL*DINNER };
  jobs.j[4] = { proj_w,                 projw_bf,                            DMODEL*2*DMODEL };
  k_cast5<<<dim3(DPROJ*DMODEL/4/256, 5), 256, 0, stream>>>(jobs);

  k_stats1<<<dim3(128, BATCH), 256, 0, stream>>>(x, pbuf);
  k_stats2<<<BATCH, 128, 0, stream>>>(pbuf, stats);
  k_t<<<dim3(32,4,2), 256, 0, stream>>>(x, gn_w, gn_b, stats, t_buf);

  EpiInProj e1{z_buf, xraw, dt_buf, (const float*)d_in[8], (const float*)d_in[16]};
  gemm_epi<EpiInProj><<<dim3(32, 37, 2), 256, 0, stream>>>(
      t_buf, DMODEL, inw_bf, DMODEL, M_TOT, DPROJ, DMODEL, e1);

  k_conv<<<dim3(5, L_SEQ/32, 2*BATCH), 256, 0, stream>>>(
      xraw, (const float*)d_in[6], (const float*)d_in[7],
            (const float*)d_in[14], (const float*)d_in[15], xconv);
  k_scan<<<2*BATCH*NH*NCHK, 256, 0, stream>>>(
      dt_buf, (const float*)d_in[9], (const float*)d_in[17], acs);
  k_states<<<2*BATCH*NCHK*NH, 256, 0, stream>>>(xconv, dt_buf, acs, states);
  k_recur<<<2*BATCH*NH*32, 256, 0, stream>>>(states, acs);
  k_cb<<<dim3(4,4,2*BATCH*NCHK), 256, 0, stream>>>(xconv, cb);
  k_y_mfma<<<2*BATCH*NCHK*NH*2, 256, 0, stream>>>(xconv, dt_buf, acs, cb, states, y_buf);
  k_gaterms<<<2*M_TOT, 256, 0, stream>>>(
      z_buf, (const float*)d_in[11], (const float*)d_in[19], xconv,
      (const float*)d_in[10], (const float*)d_in[18], y_buf);

  gemm_atomic2<<<dim3(32, 4, 8), 256, 0, stream>>>(
      y_buf, DINNER, outw_bf, DINNER, M_TOT, DMODEL, DINNER, scr);
  post_outproj<<<2*M_TOT/8, 256, 0, stream>>>(scr, t_buf, r_buf);

  gemm_atomic<<<dim3(32, 4, 4), 256, 0, stream>>>(
      r_buf, 2*DMODEL, projw_bf, 2*DMODEL, M_TOT, DMODEL, 2*DMODEL, scr_fin);
  post_final<<<dim3(32, 4, 2), 256, 0, stream>>>(scr_fin, x, proj_b, out);
}

// Round 4
// 263.353 us; speedup vs baseline: 1.6161x; 1.1611x over previous
//
#include <hip/hip_runtime.h>
#include <hip/hip_bf16.h>
#include <math.h>

using bf16 = __hip_bfloat16;

#define L_SEQ   2048
#define DMODEL  256
#define DINNER  1024
#define DSTATE  128
#define NH      16
#define HD      64
#define CONVDIM 1280
#define DPROJ   2320
#define NCHK    8
#define CT      256
#define BATCH   2
#define M_TOT   (BATCH*L_SEQ)

#define ACS_N   (BATCH*NH*NCHK*CT)
#define ST_N    ((size_t)BATCH*NCHK*NH*HD*DSTATE)
#define CB_N    ((size_t)BATCH*NCHK*CT*CT)

typedef __bf16 bf16x8_t __attribute__((ext_vector_type(8)));
typedef __bf16 bf16x4_t __attribute__((ext_vector_type(4)));
typedef float  f32x4_t  __attribute__((ext_vector_type(4)));

__device__ __forceinline__ float tof(bf16 v){ return __bfloat162float(v); }
__device__ __forceinline__ bf16  tob(float v){ return __float2bfloat16(v); }
__device__ __forceinline__ float expdec(float a){ return expf(fminf(a, 0.f)); }

// ---------------- fp32 -> bf16 cast (all weights, one launch) --------------------
struct CastJob  { const float* src; bf16* dst; int n; };
struct CastJobs { CastJob j[5]; };

__global__ __launch_bounds__(256) void k_cast5(CastJobs jobs){
  CastJob jb = jobs.j[blockIdx.y];
  int i = (blockIdx.x*256 + threadIdx.x)*4;
  if (i < jb.n){
    float4 v = *(const float4*)(jb.src + i);
    jb.dst[i]   = tob(v.x); jb.dst[i+1] = tob(v.y);
    jb.dst[i+2] = tob(v.z); jb.dst[i+3] = tob(v.w);
  }
}

// ---------------- prep: transpose outw (bf16) + psum = Pf+Pb (bf16) --------------
__global__ __launch_bounds__(256) void k_prep(const bf16* __restrict__ ow, const float* __restrict__ pw,
                                              bf16* __restrict__ owt, bf16* __restrict__ psum){
  int bz = blockIdx.x;
  int t = threadIdx.x;
  if (bz < 128){
    // transpose outw_bf [dir][256 j][1024 k] -> owt [dir][1024 k][256 j], 64x64 tiles
    int dir = bz >> 6; int tid = bz & 63;
    int k0 = (tid >> 2)*64, j0 = (tid & 3)*64;
    const bf16* src = ow + (size_t)dir*DMODEL*DINNER;
    bf16* dst = owt + (size_t)dir*DINNER*DMODEL;
    __shared__ __bf16 tile[64][65];
    #pragma unroll
    for (int it = 0; it < 2; ++it){
      int idx = t + it*256; int jj = idx >> 3; int k8 = (idx & 7)*8;
      bf16x8_t v = *(const bf16x8_t*)&src[(size_t)(j0+jj)*DINNER + k0 + k8];
      #pragma unroll
      for (int i = 0; i < 8; ++i) tile[k8+i][jj] = v[i];
    }
    __syncthreads();
    #pragma unroll
    for (int it = 0; it < 2; ++it){
      int idx = t + it*256; int kr = idx >> 3; int j8 = (idx & 7)*8;
      bf16x8_t o;
      #pragma unroll
      for (int i = 0; i < 8; ++i) o[i] = tile[kr][j8+i];
      *(bf16x8_t*)&dst[(size_t)(k0+kr)*DMODEL + j0 + j8] = o;
    }
  } else {
    // psum[n][j] = pw[n][j] + pw[n][256+j], bf16
    int i = ((bz - 128)*256 + t)*8;
    int n = i >> 8, j = i & 255;
    const float* row = pw + (size_t)n*(2*DMODEL);
    bf16x8_t o;
    #pragma unroll
    for (int c = 0; c < 8; ++c) o[c] = (__bf16)(row[j+c] + row[256+j+c]);
    *(bf16x8_t*)&psum[i] = o;
  }
}

// ---------------- batch stats ----------------------------------------------------
__global__ __launch_bounds__(256) void k_stats1(const float* __restrict__ x, float2* __restrict__ pbuf){
  int b = blockIdx.y, blk = blockIdx.x, t = threadIdx.x;
  const float4* p = (const float4*)(x + (size_t)b*(DMODEL*L_SEQ) + (size_t)blk*4096);
  float s = 0.f, ss = 0.f;
  #pragma unroll
  for (int k = 0; k < 4; ++k){
    float4 v = p[t + k*256];
    s  += v.x + v.y + v.z + v.w;
    ss += v.x*v.x + v.y*v.y + v.z*v.z + v.w*v.w;
  }
  for (int o = 32; o > 0; o >>= 1){ s += __shfl_down(s, o, 64); ss += __shfl_down(ss, o, 64); }
  __shared__ float sh[8];
  if ((t & 63) == 0){ sh[(t>>6)*2] = s; sh[(t>>6)*2+1] = ss; }
  __syncthreads();
  if (t == 0){
    s  = sh[0]+sh[2]+sh[4]+sh[6];
    ss = sh[1]+sh[3]+sh[5]+sh[7];
    pbuf[b*128 + blk] = make_float2(s, ss);
  }
}

__global__ __launch_bounds__(128) void k_stats2(const float2* __restrict__ pbuf, float* __restrict__ stats){
  int b = blockIdx.x, t = threadIdx.x;
  float2 v = pbuf[b*128 + t];
  float s = v.x, ss = v.y;
  for (int o = 32; o > 0; o >>= 1){ s += __shfl_down(s, o, 64); ss += __shfl_down(ss, o, 64); }
  __shared__ float sh[4];
  if ((t & 63) == 0){ sh[(t>>6)*2] = s; sh[(t>>6)*2+1] = ss; }
  __syncthreads();
  if (t == 0){
    s  = sh[0]+sh[2];
    ss = sh[1]+sh[3];
    float inv = 1.f/(float)(DMODEL*L_SEQ);
    float mu = s*inv, var = ss*inv - mu*mu;
    stats[0 + b*2] = mu; stats[1 + b*2] = rsqrtf(fmaxf(var, 0.f) + 1.1920929e-07f);
  }
}

// ---------------- GroupNorm + transpose ------------------------------------------
__global__ __launch_bounds__(256) void k_t(const float* __restrict__ x, const float* __restrict__ gw,
                                           const float* __restrict__ gb, const float* __restrict__ stats,
                                           bf16* __restrict__ t_out){
  __shared__ float tile[64][65];
  int l0 = blockIdx.x*64, c0 = blockIdx.y*64, b = blockIdx.z;
  float mu = stats[b*2], istd = stats[b*2+1];
  int tid = threadIdx.x;
  int lx = tid & 63, cy = tid >> 6;
  for (int cc = cy; cc < 64; cc += 4){
    float v = x[(size_t)b*DMODEL*L_SEQ + (size_t)(c0+cc)*L_SEQ + l0+lx];
    tile[cc][lx] = (v - mu)*istd;
  }
  __syncthreads();
  int cx = tid & 63, ly = tid >> 6;
  float w = gw[c0+cx], bb = gb[c0+cx];
  for (int ll = ly; ll < 64; ll += 4)
    t_out[((size_t)(b*L_SEQ) + l0+ll)*DMODEL + c0+cx] = tob(tile[cx][ll]*w + bb);
}

// ---------------- MFMA GEMM 128x64, dir-batched (z), direct epilogue -------------
template<class Epi>
__global__ __launch_bounds__(256) void gemm_epi(const bf16* __restrict__ A, int lda,
                                                const bf16* __restrict__ B, int ldb,
                                                int M, int N, int K, Epi epi){
  __shared__ __align__(16) bf16 lds[2][(128+64)*40];
  int dir = blockIdx.z;
  const bf16* Bd = B + (size_t)dir*(size_t)N*ldb;
  int m0 = blockIdx.x*128, n0 = blockIdx.y*64;
  int t = threadIdx.x;
  int wave = t >> 6, lane = t & 63;
  int wm = (wave & 1)*64, wn = (wave >> 1)*32;
  int lrow = lane & 15, quad = lane >> 4, lk8 = quad*8;

  int r0 = t >> 2, o0 = (t & 3)*8;
  int r1 = r0 + 64;
  int am0 = m0 + r0, am1 = m0 + r1;
  if (dir){
    am0 = (am0 & ~(L_SEQ-1)) | ((L_SEQ-1) - (am0 & (L_SEQ-1)));
    am1 = (am1 & ~(L_SEQ-1)) | ((L_SEQ-1) - (am1 & (L_SEQ-1)));
  }
  int bn = n0 + r0; if (bn > N-1) bn = N-1;
  const bf16* Ap0 = A + (size_t)am0*lda + o0;
  const bf16* Ap1 = A + (size_t)am1*lda + o0;
  const bf16* Bp  = Bd + (size_t)bn*ldb + o0;

  f32x4_t acc[4][2];
  #pragma unroll
  for (int i = 0; i < 4; ++i){ acc[i][0] = (f32x4_t){0,0,0,0}; acc[i][1] = (f32x4_t){0,0,0,0}; }

  int nit = K >> 5;
  uint4 a0 = *(const uint4*)Ap0;
  uint4 a1 = *(const uint4*)Ap1;
  uint4 b0 = *(const uint4*)Bp;
  int st = 0;
  *(uint4*)&lds[0][r0*40 + o0] = a0;
  *(uint4*)&lds[0][r1*40 + o0] = a1;
  *(uint4*)&lds[0][(128 + r0)*40 + o0] = b0;
  __syncthreads();
  for (int it = 0; it < nit; ++it){
    bool more = (it+1 < nit);
    if (more){
      int kk = (it+1) << 5;
      a0 = *(const uint4*)(Ap0 + kk);
      a1 = *(const uint4*)(Ap1 + kk);
      b0 = *(const uint4*)(Bp + kk);
    }
    const bf16* cs = lds[st];
    bf16x8_t af[4], bfr[2];
    #pragma unroll
    for (int mi = 0; mi < 4; ++mi) af[mi] = *(const bf16x8_t*)&cs[(wm + mi*16 + lrow)*40 + lk8];
    #pragma unroll
    for (int ni = 0; ni < 2; ++ni) bfr[ni] = *(const bf16x8_t*)&cs[(128 + wn + ni*16 + lrow)*40 + lk8];
    #pragma unroll
    for (int mi = 0; mi < 4; ++mi)
      #pragma unroll
      for (int ni = 0; ni < 2; ++ni)
        acc[mi][ni] = __builtin_amdgcn_mfma_f32_16x16x32_bf16(af[mi], bfr[ni], acc[mi][ni], 0, 0, 0);
    if (more){
      st ^= 1;
      *(uint4*)&lds[st][r0*40 + o0] = a0;
      *(uint4*)&lds[st][r1*40 + o0] = a1;
      *(uint4*)&lds[st][(128 + r0)*40 + o0] = b0;
      __syncthreads();
    }
  }
  #pragma unroll
  for (int mi = 0; mi < 4; ++mi)
    #pragma unroll
    for (int ni = 0; ni < 2; ++ni)
      #pragma unroll
      for (int r = 0; r < 4; ++r){
        int m = m0 + wm + mi*16 + quad*4 + r;
        int n = n0 + wn + ni*16 + lrow;
        if (m < M && n < N) epi(dir, m, n, acc[mi][ni][r]);
      }
}

struct EpiInProj {
  bf16* z; bf16* xbc; float* dt; const float* db0; const float* db1;
  __device__ void operator()(int dir, int m, int n, float v) const {
    size_t mm = (size_t)dir*M_TOT + m;
    if (n < DINNER) z[mm*DINNER + n] = tob(v);
    else if (n < DINNER+CONVDIM) xbc[mm*CONVDIM + (n-DINNER)] = tob(v);
    else {
      int h = n - (DINNER+CONVDIM);
      float xx = v + (dir ? db1 : db0)[h];
      dt[mm*NH + h] = (xx > 20.f) ? xx : log1pf(expf(xx));
    }
  }
};

// ---------------- W = P_dir @ outw_dir  (256x1024, K=256), bf16 out --------------
__global__ __launch_bounds__(256) void gemm_w(const bf16* __restrict__ P, const bf16* __restrict__ owt,
                                              bf16* __restrict__ W){
  __shared__ __align__(16) bf16 lds[2][(128+64)*40];
  int dir = blockIdx.z;
  int m0 = blockIdx.x*128, n0 = blockIdx.y*64;
  int t = threadIdx.x;
  int wave = t >> 6, lane = t & 63;
  int wm = (wave & 1)*64, wn = (wave >> 1)*32;
  int lrow = lane & 15, quad = lane >> 4, lk8 = quad*8;

  int r0 = t >> 2, o0 = (t & 3)*8;
  int r1 = r0 + 64;
  const bf16* Ap0 = P + (size_t)(m0 + r0)*(2*DMODEL) + dir*DMODEL + o0;
  const bf16* Ap1 = P + (size_t)(m0 + r1)*(2*DMODEL) + dir*DMODEL + o0;
  const bf16* Bp  = owt + (size_t)dir*DINNER*DMODEL + (size_t)(n0 + r0)*DMODEL + o0;

  f32x4_t acc[4][2];
  #pragma unroll
  for (int i = 0; i < 4; ++i){ acc[i][0] = (f32x4_t){0,0,0,0}; acc[i][1] = (f32x4_t){0,0,0,0}; }

  int nit = DMODEL >> 5;  // 8
  uint4 a0 = *(const uint4*)Ap0;
  uint4 a1 = *(const uint4*)Ap1;
  uint4 b0 = *(const uint4*)Bp;
  int st = 0;
  *(uint4*)&lds[0][r0*40 + o0] = a0;
  *(uint4*)&lds[0][r1*40 + o0] = a1;
  *(uint4*)&lds[0][(128 + r0)*40 + o0] = b0;
  __syncthreads();
  for (int it = 0; it < nit; ++it){
    bool more = (it+1 < nit);
    if (more){
      int kk = (it+1) << 5;
      a0 = *(const uint4*)(Ap0 + kk);
      a1 = *(const uint4*)(Ap1 + kk);
      b0 = *(const uint4*)(Bp + kk);
    }
    const bf16* cs = lds[st];
    bf16x8_t af[4], bfr[2];
    #pragma unroll
    for (int mi = 0; mi < 4; ++mi) af[mi] = *(const bf16x8_t*)&cs[(wm + mi*16 + lrow)*40 + lk8];
    #pragma unroll
    for (int ni = 0; ni < 2; ++ni) bfr[ni] = *(const bf16x8_t*)&cs[(128 + wn + ni*16 + lrow)*40 + lk8];
    #pragma unroll
    for (int mi = 0; mi < 4; ++mi)
      #pragma unroll
      for (int ni = 0; ni < 2; ++ni)
        acc[mi][ni] = __builtin_amdgcn_mfma_f32_16x16x32_bf16(af[mi], bfr[ni], acc[mi][ni], 0, 0, 0);
    if (more){
      st ^= 1;
      *(uint4*)&lds[st][r0*40 + o0] = a0;
      *(uint4*)&lds[st][r1*40 + o0] = a1;
      *(uint4*)&lds[st][(128 + r0)*40 + o0] = b0;
      __syncthreads();
    }
  }
  bf16* Wd = W + (size_t)dir*DMODEL*DINNER;
  #pragma unroll
  for (int mi = 0; mi < 4; ++mi)
    #pragma unroll
    for (int ni = 0; ni < 2; ++ni)
      #pragma unroll
      for (int r = 0; r < 4; ++r){
        int m = m0 + wm + mi*16 + quad*4 + r;
        int n = n0 + wn + ni*16 + lrow;
        Wd[(size_t)m*DINNER + n] = tob(acc[mi][ni][r]);
      }
}

// ---------------- fused final GEMM: scr += y_f@Wf^T + y_b[flip]@Wb^T + t@psum^T --
__global__ __launch_bounds__(256) void gemm_final(const bf16* __restrict__ y, const bf16* __restrict__ tb,
                                                  const bf16* __restrict__ W, const bf16* __restrict__ psum,
                                                  float* __restrict__ scr){
  __shared__ __align__(16) bf16 lds[2][(128+64)*40];
  int kz = blockIdx.z;
  const bf16 *Ab, *Bb; int lda, ldb, K; int rev = 0;
  if (kz < 4){
    int dir = kz >> 1; int koff = (kz & 1)*512;
    Ab = y + (size_t)dir*M_TOT*DINNER + koff; lda = DINNER; K = 512;
    Bb = W + (size_t)dir*DMODEL*DINNER + koff; ldb = DINNER;
    rev = dir;
  } else {
    Ab = tb; lda = DMODEL; K = DMODEL;
    Bb = psum; ldb = DMODEL;
  }
  int m0 = blockIdx.x*128, n0 = blockIdx.y*64;
  int t = threadIdx.x;
  int wave = t >> 6, lane = t & 63;
  int wm = (wave & 1)*64, wn = (wave >> 1)*32;
  int lrow = lane & 15, quad = lane >> 4, lk8 = quad*8;

  int r0 = t >> 2, o0 = (t & 3)*8;
  int r1 = r0 + 64;
  int am0 = m0 + r0, am1 = m0 + r1;
  if (rev){
    am0 = (am0 & ~(L_SEQ-1)) | ((L_SEQ-1) - (am0 & (L_SEQ-1)));
    am1 = (am1 & ~(L_SEQ-1)) | ((L_SEQ-1) - (am1 & (L_SEQ-1)));
  }
  const bf16* Ap0 = Ab + (size_t)am0*lda + o0;
  const bf16* Ap1 = Ab + (size_t)am1*lda + o0;
  const bf16* Bp  = Bb + (size_t)(n0 + r0)*ldb + o0;

  f32x4_t acc[4][2];
  #pragma unroll
  for (int i = 0; i < 4; ++i){ acc[i][0] = (f32x4_t){0,0,0,0}; acc[i][1] = (f32x4_t){0,0,0,0}; }

  int nit = K >> 5;
  uint4 a0 = *(const uint4*)Ap0;
  uint4 a1 = *(const uint4*)Ap1;
  uint4 b0 = *(const uint4*)Bp;
  int st = 0;
  *(uint4*)&lds[0][r0*40 + o0] = a0;
  *(uint4*)&lds[0][r1*40 + o0] = a1;
  *(uint4*)&lds[0][(128 + r0)*40 + o0] = b0;
  __syncthreads();
  for (int it = 0; it < nit; ++it){
    bool more = (it+1 < nit);
    if (more){
      int kk = (it+1) << 5;
      a0 = *(const uint4*)(Ap0 + kk);
      a1 = *(const uint4*)(Ap1 + kk);
      b0 = *(const uint4*)(Bp + kk);
    }
    const bf16* cs = lds[st];
    bf16x8_t af[4], bfr[2];
    #pragma unroll
    for (int mi = 0; mi < 4; ++mi) af[mi] = *(const bf16x8_t*)&cs[(wm + mi*16 + lrow)*40 + lk8];
    #pragma unroll
    for (int ni = 0; ni < 2; ++ni) bfr[ni] = *(const bf16x8_t*)&cs[(128 + wn + ni*16 + lrow)*40 + lk8];
    #pragma unroll
    for (int mi = 0; mi < 4; ++mi)
      #pragma unroll
      for (int ni = 0; ni < 2; ++ni)
        acc[mi][ni] = __builtin_amdgcn_mfma_f32_16x16x32_bf16(af[mi], bfr[ni], acc[mi][ni], 0, 0, 0);
    if (more){
      st ^= 1;
      *(uint4*)&lds[st][r0*40 + o0] = a0;
      *(uint4*)&lds[st][r1*40 + o0] = a1;
      *(uint4*)&lds[st][(128 + r0)*40 + o0] = b0;
      __syncthreads();
    }
  }
  #pragma unroll
  for (int mi = 0; mi < 4; ++mi)
    #pragma unroll
    for (int ni = 0; ni < 2; ++ni)
      #pragma unroll
      for (int r = 0; r < 4; ++r){
        int m = m0 + wm + mi*16 + quad*4 + r;
        int n = n0 + wn + ni*16 + lrow;
        atomicAdd(&scr[(size_t)m*DMODEL + n], acc[mi][ni][r]);
      }
}

// ---------------- post: final epilogue (scr + pb + x -> out, transposed) ---------
__global__ __launch_bounds__(256) void post_final(const float* __restrict__ scr, const float* __restrict__ x,
                                                  const float* __restrict__ pb, float* __restrict__ out){
  __shared__ float tile[64][65];
  int l0 = blockIdx.x*64, n0 = blockIdx.y*64, b = blockIdx.z;
  int tid = threadIdx.x;
  int nx = tid & 63, ly = tid >> 6;
  for (int ll = ly; ll < 64; ll += 4)
    tile[ll][nx] = scr[((size_t)(b*L_SEQ) + l0+ll)*DMODEL + n0+nx];
  __syncthreads();
  int lx = tid & 63, ny = tid >> 6;
  for (int nn = ny; nn < 64; nn += 4){
    int n = n0 + nn;
    size_t xi = (size_t)b*DMODEL*L_SEQ + (size_t)n*L_SEQ + l0+lx;
    out[xi] = tile[lx][nn] + pb[n] + x[xi];
  }
}

// ---------------- depthwise causal conv + SiLU, vectorized rolling window --------
__global__ __launch_bounds__(256) void k_conv(const bf16* __restrict__ xraw, const float* __restrict__ cw0,
                                              const float* __restrict__ cb0, const float* __restrict__ cw1,
                                              const float* __restrict__ cb1, bf16* __restrict__ xconv){
  int t = threadIdx.x;
  int tx = t & 31, ty = t >> 5;
  int ch0 = blockIdx.x*256 + tx*8;
  int z = blockIdx.z; int b = z & 1, dir = z >> 1;
  int lbase = blockIdx.y*32 + ty*4;
  const float* cw = dir ? cw1 : cw0;
  const float* cb = dir ? cb1 : cb0;
  const bf16* xr = xraw  + (size_t)dir*((size_t)M_TOT*CONVDIM) + (size_t)(b*L_SEQ)*CONVDIM + ch0;
  bf16* xcv      = xconv + (size_t)dir*((size_t)M_TOT*CONVDIM) + (size_t)(b*L_SEQ)*CONVDIM + ch0;

  float wk[4][8];
  #pragma unroll
  for (int c = 0; c < 8; ++c){
    float4 w = *(const float4*)&cw[(ch0+c)*4];
    wk[0][c] = w.x; wk[1][c] = w.y; wk[2][c] = w.z; wk[3][c] = w.w;
  }
  float bias[8];
  {
    float4 b0v = *(const float4*)&cb[ch0];
    float4 b1v = *(const float4*)&cb[ch0+4];
    bias[0]=b0v.x; bias[1]=b0v.y; bias[2]=b0v.z; bias[3]=b0v.w;
    bias[4]=b1v.x; bias[5]=b1v.y; bias[6]=b1v.z; bias[7]=b1v.w;
  }

  bf16x8_t zero;
  #pragma unroll
  for (int c = 0; c < 8; ++c) zero[c] = (__bf16)0.f;

  bf16x8_t win[4];
  #pragma unroll
  for (int k = 0; k < 3; ++k){
    int ls = lbase - 3 + k;
    win[k] = (ls >= 0) ? *(const bf16x8_t*)&xr[(size_t)ls*CONVDIM] : zero;
  }
  #pragma unroll
  for (int i = 0; i < 4; ++i){
    int l = lbase + i;
    win[3] = *(const bf16x8_t*)&xr[(size_t)l*CONVDIM];
    bf16x8_t outv;
    #pragma unroll
    for (int c = 0; c < 8; ++c){
      float a = bias[c] + (float)win[0][c]*wk[0][c] + (float)win[1][c]*wk[1][c]
                        + (float)win[2][c]*wk[2][c] + (float)win[3][c]*wk[3][c];
      outv[c] = (__bf16)(a / (1.f + expf(-a)));
    }
    *(bf16x8_t*)&xcv[(size_t)l*CONVDIM] = outv;
    win[0] = win[1]; win[1] = win[2]; win[2] = win[3];
  }
}

// ---------------- per-(dir,b,h,chunk) inclusive cumsum of A ----------------------
__global__ __launch_bounds__(256) void k_scan(const float* __restrict__ dt, const float* __restrict__ Al0,
                                              const float* __restrict__ Al1, float* __restrict__ A_cs){
  int id0 = blockIdx.x;
  int dir = id0 >> 8; int id = id0 & 255;
  int ch = id & 7; int bh = id >> 3; int h = bh & 15; int b = bh >> 4;
  const float* Alog = dir ? Al1 : Al0;
  const float* dtp = dt + (size_t)dir*((size_t)M_TOT*NH);
  float* acsd = A_cs + (size_t)dir*ACS_N;
  int l = threadIdx.x;
  int gl = ch*CT + l;
  float a = -expf(Alog[h]) * dtp[((size_t)(b*L_SEQ)+gl)*NH + h];
  __shared__ float s[256];
  s[l] = a; __syncthreads();
  for (int off = 1; off < 256; off <<= 1){
    float v = (l >= off) ? s[l-off] : 0.f;
    __syncthreads();
    s[l] += v;
    __syncthreads();
  }
  acsd[(size_t)id*CT + l] = s[l];
}

// ---------------- per-chunk states via MFMA: states[p][n] = sum_l (w*X)[l][p]*B[l][n]
__global__ __launch_bounds__(256) void k_states(const bf16* __restrict__ xconv, const float* __restrict__ dt,
                                                const float* __restrict__ A_cs, float* __restrict__ states){
  int id0 = blockIdx.x;
  int dir = id0 >> 8; int id = id0 & 255;
  int h = id & 15; int bc = id >> 4; int ch = bc & 7; int b = bc >> 3;
  int t = threadIdx.x;
  __shared__ float w_s[CT];
  __shared__ __align__(16) __bf16 Xt[64*72];    // [p][l-tile], group-swizzled
  __shared__ __align__(16) __bf16 Bt[128*72];   // [n][l-tile], group-swizzled
  const bf16* xc = xconv + (size_t)dir*((size_t)M_TOT*CONVDIM);
  const float* dtp = dt + (size_t)dir*((size_t)M_TOT*NH);
  const float* acs = A_cs + (size_t)dir*ACS_N + (size_t)((b*NH+h)*NCHK + ch)*CT;
  size_t rowbase = (size_t)(b*L_SEQ) + ch*CT;
  float alast = acs[CT-1];
  w_s[t] = dtp[(rowbase + t)*NH + h] * expdec(alast - acs[t]);
  __syncthreads();

  int wave = t >> 6, lane = t & 63, lrow = lane & 15, quad = lane >> 4;
  f32x4_t acc[8];
  #pragma unroll
  for (int i = 0; i < 8; ++i) acc[i] = (f32x4_t){0.f,0.f,0.f,0.f};

  for (int kt = 0; kt < 4; ++kt){
    int l0 = kt*64;
    #pragma unroll
    for (int it = 0; it < 2; ++it){
      int idx = t + it*256; int l = idx >> 3; int p0 = (idx & 7)*8;
      bf16x8_t v = *(const bf16x8_t*)&xc[(rowbase + l0 + l)*CONVDIM + h*HD + p0];
      float w = w_s[l0 + l];
      int col = (((l>>3) ^ ((p0>>3)&7))<<3) | (l&7);
      #pragma unroll
      for (int j = 0; j < 8; ++j) Xt[(p0+j)*72 + col] = (__bf16)((float)v[j]*w);
    }
    #pragma unroll
    for (int it = 0; it < 4; ++it){
      int idx = t + it*256; int l = idx >> 4; int n0 = (idx & 15)*8;
      bf16x8_t v = *(const bf16x8_t*)&xc[(rowbase + l0 + l)*CONVDIM + DINNER + n0];
      int col = (((l>>3) ^ ((n0>>3)&7))<<3) | (l&7);
      #pragma unroll
      for (int j = 0; j < 8; ++j) Bt[(n0+j)*72 + col] = v[j];
    }
    __syncthreads();
    int arow = wave*16 + lrow;
    #pragma unroll
    for (int ks = 0; ks < 2; ++ks){
      int kg = ks*4 + quad;
      bf16x8_t af = *(const bf16x8_t*)&Xt[arow*72 + ((kg ^ ((arow>>3)&7))<<3)];
      #pragma unroll
      for (int nt = 0; nt < 8; ++nt){
        int brow = nt*16 + lrow;
        bf16x8_t bq = *(const bf16x8_t*)&Bt[brow*72 + ((kg ^ ((brow>>3)&7))<<3)];
        acc[nt] = __builtin_amdgcn_mfma_f32_16x16x32_bf16(af, bq, acc[nt], 0, 0, 0);
      }
    }
    __syncthreads();
  }
  float* so = states + (size_t)dir*ST_N + (size_t)id*HD*DSTATE;
  int m = wave*16 + quad*4;
  #pragma unroll
  for (int nt = 0; nt < 8; ++nt)
    #pragma unroll
    for (int r = 0; r < 4; ++r)
      so[(size_t)(m+r)*DSTATE + nt*16 + lrow] = acc[nt][r];
}

// ---------------- inter-chunk recurrence (one element per thread) ----------------
__global__ __launch_bounds__(256) void k_recur(float* __restrict__ states, const float* __restrict__ A_cs){
  int blk = blockIdx.x;
  int bh2 = blk >> 5;
  int e = (blk & 31)*256 + threadIdx.x;
  int dir = bh2 >> 5; int bh = bh2 & 31;
  int h = bh & 15, b = bh >> 4;
  const float* ac = A_cs + (size_t)dir*ACS_N;
  float* st = states + (size_t)dir*ST_N;
  float s = 0.f;
  #pragma unroll
  for (int ch = 0; ch < NCHK; ++ch){
    float dec = expdec(ac[((size_t)(bh*NCHK+ch))*CT + CT-1]);
    size_t off = (size_t)(((b*NCHK+ch)*NH)+h)*HD*DSTATE + e;
    float cur = st[off];
    st[off] = s;
    s = s*dec + cur;
  }
}

// ---------------- CB = C · B^T per (dir,b,chunk), MFMA ---------------------------
__global__ __launch_bounds__(256) void k_cb(const bf16* __restrict__ xconv, float* __restrict__ CB){
  int zz = blockIdx.z;
  int dir = zz >> 4; int b = (zz >> 3) & 1; int ch = zz & 7;
  int m0 = blockIdx.x*64, n0 = blockIdx.y*64;
  if (n0 > m0) return;
  const bf16* base = xconv + (size_t)dir*((size_t)M_TOT*CONVDIM) + (size_t)(b*L_SEQ + ch*CT)*CONVDIM;
  const bf16* Crow = base + DINNER + DSTATE;
  const bf16* Brow = base + DINNER;
  __shared__ __align__(16) __bf16 As[64*136];
  __shared__ __align__(16) __bf16 Bs[64*136];
  int t = threadIdx.x;
  int r = t >> 2, o0 = (t & 3)*32;
  #pragma unroll
  for (int j = 0; j < 4; ++j){
    *(bf16x8_t*)&As[r*136 + o0 + j*8] = *(const bf16x8_t*)&Crow[(size_t)(m0+r)*CONVDIM + o0 + j*8];
    *(bf16x8_t*)&Bs[r*136 + o0 + j*8] = *(const bf16x8_t*)&Brow[(size_t)(n0+r)*CONVDIM + o0 + j*8];
  }
  __syncthreads();
  int wave = t >> 6, lane = t & 63, lrow = lane & 15, quad = lane >> 4;
  int wm = wave*16;
  f32x4_t acc[4];
  #pragma unroll
  for (int i = 0; i < 4; ++i) acc[i] = (f32x4_t){0.f,0.f,0.f,0.f};
  #pragma unroll
  for (int ks = 0; ks < 4; ++ks){
    bf16x8_t af = *(const bf16x8_t*)&As[(wm+lrow)*136 + ks*32 + quad*8];
    #pragma unroll
    for (int nt = 0; nt < 4; ++nt){
      bf16x8_t bq = *(const bf16x8_t*)&Bs[(nt*16+lrow)*136 + ks*32 + quad*8];
      acc[nt] = __builtin_amdgcn_mfma_f32_16x16x32_bf16(af, bq, acc[nt], 0, 0, 0);
    }
  }
  float* outp = CB + (size_t)dir*CB_N + (size_t)(b*NCHK+ch)*CT*CT;
  #pragma unroll
  for (int nt = 0; nt < 4; ++nt)
    #pragma unroll
    for (int r2 = 0; r2 < 4; ++r2)
      outp[(size_t)(m0+wm+quad*4+r2)*CT + n0+nt*16+lrow] = acc[nt][r2];
}

// ---------------- Y = (L*CB)@X + exp(Acs)*(C@NS)  (MFMA, dir-batched) ------------
__global__ __launch_bounds__(256) void k_y_mfma(const bf16* __restrict__ xconv, const float* __restrict__ dt,
                                                const float* __restrict__ A_cs, const float* __restrict__ CB,
                                                const float* __restrict__ ns, bf16* __restrict__ y){
  int id0 = blockIdx.x;
  int dir = id0 >> 9; int id = id0 & 511;
  int hh = id & 1; int r = id >> 1; int h = r & 15; int bc = r >> 4; int ch = bc & 7; int b = bc >> 3;
  int t = threadIdx.x;
  int lane = t & 63;
  int lrow = lane & 15, quad = lane >> 4;

  __shared__ __align__(16) bf16 Xs[64*264];
  __shared__ __align__(16) bf16 NSs[64*136];
  __shared__ float acs_s[CT];

  const bf16* xc = xconv + (size_t)dir*((size_t)M_TOT*CONVDIM);
  const float* dtp = dt + (size_t)dir*((size_t)M_TOT*NH);
  const float* acs = A_cs + (size_t)dir*ACS_N + (size_t)((b*NH+h)*NCHK + ch)*CT;
  const float* cbz = CB + (size_t)dir*CB_N + (size_t)(b*NCHK+ch)*CT*CT;
  const float* nsp = ns + (size_t)dir*ST_N + (size_t)(((b*NCHK+ch)*NH)+h)*HD*DSTATE;
  bf16* yp = y + (size_t)dir*((size_t)M_TOT*DINNER);
  size_t rowbase = (size_t)(b*L_SEQ + ch*CT);
  acs_s[t] = acs[t];

  // X staging: vectorized bf16x8 loads, group-swizzled scatter into [p][s] layout
  #pragma unroll
  for (int it = 0; it < 8; ++it){
    int idx = t + it*256;
    int s = idx >> 3, p0 = (idx & 7)*8;
    float dtv = dtp[(rowbase + s)*NH + h];
    bf16x8_t v = *(const bf16x8_t*)&xc[(rowbase + s)*CONVDIM + h*HD + p0];
    int col = ((((s>>3) ^ ((p0>>3)&7)))<<3) | (s&7);
    #pragma unroll
    for (int j = 0; j < 8; ++j)
      Xs[(p0+j)*264 + col] = tob((float)v[j] * dtv);
  }
  for (int it = 0; it < 8; ++it){
    int idx = t + it*256;
    int n4 = (idx & 31)*4, p = idx >> 5;
    float4 v = *(const float4*)(nsp + p*DSTATE + n4);
    bf16* w = &NSs[p*136 + n4];
    w[0] = tob(v.x); w[1] = tob(v.y); w[2] = tob(v.z); w[3] = tob(v.w);
  }
  __syncthreads();

  int wave = t >> 6;
  int row0 = hh*128 + wave*32;
  float al0 = acs_s[row0 + lrow];
  float al1 = acs_s[row0 + 16 + lrow];
  float acs_r0 = acs_s[row0];

  f32x4_t acc[2][4];
  #pragma unroll
  for (int i = 0; i < 2; ++i)
    #pragma unroll
    for (int j = 0; j < 4; ++j) acc[i][j] = (f32x4_t){0.f,0.f,0.f,0.f};

  int nst = (row0 + 32) >> 5;
  for (int st = 0; st < nst; ++st){
    int s0 = st*32;
    if (s0 + 31 < row0 && (acs_r0 - acs_s[s0+31]) < -30.f) continue;
    int sg = (s0 >> 3) + quad;
    bf16x8_t bq[4];
    #pragma unroll
    for (int nt = 0; nt < 4; ++nt){
      int brow = nt*16 + lrow;
      bq[nt] = *(const bf16x8_t*)&Xs[brow*264 + ((sg ^ ((brow>>3)&7))<<3)];
    }
    bf16x8_t af[2];
    #pragma unroll
    for (int mt = 0; mt < 2; ++mt){
      int l = row0 + mt*16 + lrow;
      float al = mt ? al1 : al0;
      const float* cbrow = cbz + (size_t)l*CT + s0 + quad*8;
      float4 c0 = *(const float4*)cbrow;
      float4 c1 = *(const float4*)(cbrow + 4);
      float cv[8] = {c0.x,c0.y,c0.z,c0.w,c1.x,c1.y,c1.z,c1.w};
      union { bf16x8_t v; __bf16 e[8]; } wa;
      #pragma unroll
      for (int j = 0; j < 8; ++j){
        int s = s0 + quad*8 + j;
        float w = (s <= l) ? expf(fminf(al - acs_s[s], 0.f)) * cv[j] : 0.f;
        wa.e[j] = (__bf16)w;
      }
      af[mt] = wa.v;
    }
    #pragma unroll
    for (int mt = 0; mt < 2; ++mt)
      #pragma unroll
      for (int nt = 0; nt < 4; ++nt)
        acc[mt][nt] = __builtin_amdgcn_mfma_f32_16x16x32_bf16(af[mt], bq[nt], acc[mt][nt], 0, 0, 0);
  }

  float el0 = expf(fminf(al0, 0.f));
  float el1 = expf(fminf(al1, 0.f));
  #pragma unroll
  for (int kt = 0; kt < 4; ++kt){
    int n0 = kt*32;
    bf16x8_t bq[4];
    #pragma unroll
    for (int nt = 0; nt < 4; ++nt)
      bq[nt] = *(const bf16x8_t*)&NSs[(nt*16+lrow)*136 + n0 + quad*8];
    bf16x8_t af[2];
    #pragma unroll
    for (int mt = 0; mt < 2; ++mt){
      int l = row0 + mt*16 + lrow;
      float el = mt ? el1 : el0;
      union { bf16x8_t v; __bf16 e[8]; } cu;
      cu.v = *(const bf16x8_t*)&xc[(rowbase + l)*CONVDIM + DINNER + DSTATE + n0 + quad*8];
      union { bf16x8_t v; __bf16 e[8]; } wa;
      #pragma unroll
      for (int j = 0; j < 8; ++j) wa.e[j] = (__bf16)((float)cu.e[j] * el);
      af[mt] = wa.v;
    }
    #pragma unroll
    for (int mt = 0; mt < 2; ++mt)
      #pragma unroll
      for (int nt = 0; nt < 4; ++nt)
        acc[mt][nt] = __builtin_amdgcn_mfma_f32_16x16x32_bf16(af[mt], bq[nt], acc[mt][nt], 0, 0, 0);
  }

  #pragma unroll
  for (int mt = 0; mt < 2; ++mt)
    #pragma unroll
    for (int nt = 0; nt < 4; ++nt)
      #pragma unroll
      for (int rr = 0; rr < 4; ++rr){
        int l = row0 + mt*16 + quad*4 + rr;
        int p = nt*16 + lrow;
        yp[(rowbase + l)*DINNER + h*HD + p] = tob(acc[mt][nt][rr]);
      }
}

// ---------------- gate ((y + D*x) * silu(z)) + RMSNorm, vectorized ---------------
__global__ __launch_bounds__(256) void k_gaterms(const bf16* __restrict__ z, const float* __restrict__ nw0,
                                                 const float* __restrict__ nw1, const bf16* __restrict__ xconv,
                                                 const float* __restrict__ Dh0, const float* __restrict__ Dh1,
                                                 bf16* __restrict__ y){
  int m0 = blockIdx.x;
  int dir = m0 >> 12; int m = m0 & (M_TOT-1);
  int t = threadIdx.x;
  const float* nw = dir ? nw1 : nw0;
  const float* Dh = dir ? Dh1 : Dh0;
  int j0 = t*4;
  const bf16* zp = z + (size_t)dir*((size_t)M_TOT*DINNER) + (size_t)m*DINNER;
  const bf16* xc = xconv + (size_t)dir*((size_t)M_TOT*CONVDIM) + (size_t)m*CONVDIM;
  bf16* yp = y + (size_t)dir*((size_t)M_TOT*DINNER) + (size_t)m*DINNER;

  bf16x4_t zv = *(const bf16x4_t*)&zp[j0];
  bf16x4_t yv = *(const bf16x4_t*)&yp[j0];
  bf16x4_t xv = *(const bf16x4_t*)&xc[j0];
  float Dv = Dh[j0 >> 6];
  float v[4]; float ss = 0.f;
  #pragma unroll
  for (int c = 0; c < 4; ++c){
    float zf = (float)zv[c];
    float raw = (float)yv[c] + Dv*(float)xv[c];
    float g = raw * (zf / (1.f + expf(-zf)));
    v[c] = g; ss += g*g;
  }
  for (int o = 32; o > 0; o >>= 1) ss += __shfl_down(ss, o, 64);
  __shared__ float sh[4];
  if ((t & 63) == 0) sh[t>>6] = ss;
  __syncthreads();
  ss = sh[0]+sh[1]+sh[2]+sh[3];
  float scale = rsqrtf(ss*(1.f/DINNER) + 1e-5f);
  float4 nwv = *(const float4*)&nw[j0];
  float nws[4] = {nwv.x, nwv.y, nwv.z, nwv.w};
  bf16x4_t o;
  #pragma unroll
  for (int c = 0; c < 4; ++c) o[c] = (__bf16)(v[c]*scale*nws[c]);
  *(bf16x4_t*)&yp[j0] = o;
}

extern "C" void kernel_launch(void* const* d_in, const int* in_sizes, int n_in,
                              void* d_out, int out_size, void* d_ws, size_t ws_size,
                              hipStream_t stream){
  (void)in_sizes; (void)n_in; (void)out_size; (void)ws_size;
  const float* x      = (const float*)d_in[0];
  const float* gn_w   = (const float*)d_in[1];
  const float* gn_b   = (const float*)d_in[2];
  const float* proj_w = (const float*)d_in[3];
  const float* proj_b = (const float*)d_in[4];
  float* out = (float*)d_out;

  char* wp = (char*)d_ws;
  auto alloc = [&](size_t bytes){ void* r = (void*)wp; wp += (bytes + 255) & ~(size_t)255; return r; };
  bf16*  t_buf  = (bf16*) alloc((size_t)M_TOT*DMODEL*2);
  bf16*  z_buf  = (bf16*) alloc((size_t)2*M_TOT*DINNER*2);
  bf16*  xraw   = (bf16*) alloc((size_t)2*M_TOT*CONVDIM*2);   // reused as y (both dirs)
  bf16*  xconv  = (bf16*) alloc((size_t)2*M_TOT*CONVDIM*2);
  float* dt_buf = (float*)alloc((size_t)2*M_TOT*NH*4);
  float* acs    = (float*)alloc((size_t)2*ACS_N*4);
  float* states = (float*)alloc((size_t)2*ST_N*4);
  float* cb     = (float*)alloc((size_t)2*CB_N*4);
  float* stats  = (float*)alloc(16);
  float2* pbuf  = (float2*)alloc(BATCH*128*sizeof(float2));
  bf16*  inw_bf   = (bf16*)alloc((size_t)2*DPROJ*DMODEL*2);
  bf16*  outw_bf  = (bf16*)alloc((size_t)2*DMODEL*DINNER*2);
  bf16*  projw_bf = (bf16*)alloc((size_t)DMODEL*2*DMODEL*2);
  bf16*  owt      = (bf16*)alloc((size_t)2*DINNER*DMODEL*2);
  bf16*  wfb      = (bf16*)alloc((size_t)2*DMODEL*DINNER*2);
  bf16*  psum     = (bf16*)alloc((size_t)DMODEL*DMODEL*2);
  float* scr      = (float*)alloc((size_t)M_TOT*DMODEL*4);
  bf16*  y_buf    = xraw;   // xraw dead after conv

  (void)hipMemsetAsync(scr, 0, (size_t)M_TOT*DMODEL*4, stream);

  CastJobs jobs;
  jobs.j[0] = { (const float*)d_in[5],  inw_bf,                              DPROJ*DMODEL };
  jobs.j[1] = { (const float*)d_in[13], inw_bf + (size_t)DPROJ*DMODEL,       DPROJ*DMODEL };
  jobs.j[2] = { (const float*)d_in[12], outw_bf,                             DMODEL*DINNER };
  jobs.j[3] = { (const float*)d_in[20], outw_bf + (size_t)DMODEL*DINNER,     DMODEL*DINNER };
  jobs.j[4] = { proj_w,                 projw_bf,                            DMODEL*2*DMODEL };
  k_cast5<<<dim3(DPROJ*DMODEL/4/256, 5), 256, 0, stream>>>(jobs);

  k_prep<<<160, 256, 0, stream>>>(outw_bf, proj_w, owt, psum);
  gemm_w<<<dim3(2, 16, 2), 256, 0, stream>>>(projw_bf, owt, wfb);

  k_stats1<<<dim3(128, BATCH), 256, 0, stream>>>(x, pbuf);
  k_stats2<<<BATCH, 128, 0, stream>>>(pbuf, stats);
  k_t<<<dim3(32,4,2), 256, 0, stream>>>(x, gn_w, gn_b, stats, t_buf);

  EpiInProj e1{z_buf, xraw, dt_buf, (const float*)d_in[8], (const float*)d_in[16]};
  gemm_epi<EpiInProj><<<dim3(32, 37, 2), 256, 0, stream>>>(
      t_buf, DMODEL, inw_bf, DMODEL, M_TOT, DPROJ, DMODEL, e1);

  k_conv<<<dim3(5, L_SEQ/32, 2*BATCH), 256, 0, stream>>>(
      xraw, (const float*)d_in[6], (const float*)d_in[7],
            (const float*)d_in[14], (const float*)d_in[15], xconv);
  k_scan<<<2*BATCH*NH*NCHK, 256, 0, stream>>>(
      dt_buf, (const float*)d_in[9], (const float*)d_in[17], acs);
  k_states<<<2*BATCH*NCHK*NH, 256, 0, stream>>>(xconv, dt_buf, acs, states);
  k_recur<<<2*BATCH*NH*32, 256, 0, stream>>>(states, acs);
  k_cb<<<dim3(4,4,2*BATCH*NCHK), 256, 0, stream>>>(xconv, cb);
  k_y_mfma<<<2*BATCH*NCHK*NH*2, 256, 0, stream>>>(xconv, dt_buf, acs, cb, states, y_buf);
  k_gaterms<<<2*M_TOT, 256, 0, stream>>>(
      z_buf, (const float*)d_in[11], (const float*)d_in[19], xconv,
      (const float*)d_in[10], (const float*)d_in[18], y_buf);

  gemm_final<<<dim3(32, 4, 5), 256, 0, stream>>>(y_buf, t_buf, wfb, psum, scr);
  post_final<<<dim3(32, 4, 2), 256, 0, stream>>>(scr, x, proj_b, out);
}